// Round 1
// baseline (5083.438 us; speedup 1.0000x reference)
//
#include <hip/hip_runtime.h>
#include <math.h>

// Persistent-kernel NTM, R12: dataflow-tagged h/projections (single round trip),
// H split into pre (reductions, hides S_w wait) + post (cheap elementwise),
// next-step GEMV x/h parts hidden under the pubJ wait, last-step early exit.

#define NBLK 128
#define NTHR 512
#define Msz  16384
#define Dsz  256
#define Hsz  512
#define Isz  256
#define Tlen 128
#define RPB  128
#define NG   16
#define PUBSTR 8   // u64 stride (64B) for arrival arrays

struct Params { const float* in[34]; float* out; float* ws; };

__device__ __forceinline__ float wred64(float v){
#pragma unroll
  for (int o = 32; o > 0; o >>= 1) v += __shfl_xor(v, o, 64);
  return v;
}
__device__ __forceinline__ float wred32(float v){
#pragma unroll
  for (int o = 16; o > 0; o >>= 1) v += __shfl_xor(v, o, 32);
  return v;
}
__device__ __forceinline__ float sigm(float x){ return 1.f / (1.f + __expf(-x)); }
__device__ __forceinline__ float softplusf(float x){ return (x > 20.f) ? x : log1pf(__expf(x)); }

__device__ __forceinline__ void gstore(float* p, float v){
  __hip_atomic_store(p, v, __ATOMIC_RELAXED, __HIP_MEMORY_SCOPE_AGENT);
}
__device__ __forceinline__ float gload(const float* p){
  return __hip_atomic_load(p, __ATOMIC_RELAXED, __HIP_MEMORY_SCOPE_AGENT);
}
__device__ __forceinline__ void gstore64(unsigned long long* p, unsigned long long v){
  __hip_atomic_store(p, v, __ATOMIC_RELAXED, __HIP_MEMORY_SCOPE_AGENT);
}
__device__ __forceinline__ unsigned long long gload64(const unsigned long long* p){
  return __hip_atomic_load(p, __ATOMIC_RELAXED, __HIP_MEMORY_SCOPE_AGENT);
}
// lgkmcnt(0)-only barrier: vmcnt=63, expcnt=7, lgkmcnt=0 -> imm 0xC07F
__device__ __forceinline__ void lbar(){
  __builtin_amdgcn_s_waitcnt(0xC07F);
  __builtin_amdgcn_s_barrier();
}
// poll a tagged word until tag >= want; return payload float
__device__ __forceinline__ float pollw(const unsigned long long* p, unsigned want){
  unsigned long long k;
  do { k = gload64(p); } while ((int)((unsigned)(k >> 32) - want) < 0);
  return __uint_as_float((unsigned)k);
}

__global__ void __launch_bounds__(NTHR, 1)
ntm_kernel(Params P)
{
  const int b   = blockIdx.x;
  const int tid = threadIdx.x;
  const int wv  = tid >> 6;   // wave 0..7
  const int ln  = tid & 63;

  // ------- inputs (setup_inputs dict order) -------
  const float* inputs  = P.in[0];
  const float* mem0    = P.in[1];
  const float* read_w0 = P.in[2];
  const float* write_w0= P.in[3];
  const float* W_ih = P.in[4];
  const float* W_hh = P.in[5];
  const float* b_ih = P.in[6];
  const float* b_hh = P.in[7];
  const float* Wo   = P.in[8];
  const float* bo   = P.in[9];
  const float* r_Wk = P.in[10]; const float* r_bk = P.in[11];
  const float* r_Wb = P.in[12]; const float* r_bb = P.in[13];
  const float* r_Wg = P.in[14]; const float* r_bg = P.in[15];
  const float* r_Ws = P.in[16]; const float* r_bs = P.in[17];
  const float* r_Wp = P.in[18]; const float* r_bp = P.in[19];
  const float* w_Wk = P.in[20]; const float* w_bk = P.in[21];
  const float* w_Wb = P.in[22]; const float* w_bb = P.in[23];
  const float* w_Wg = P.in[24]; const float* w_bg = P.in[25];
  const float* w_Ws = P.in[26]; const float* w_bs = P.in[27];
  const float* w_Wp = P.in[28]; const float* w_bp = P.in[29];
  const float* w_We = P.in[30]; const float* w_be = P.in[31];
  const float* w_Wa = P.in[32]; const float* w_ba = P.in[33];
  float* out = P.out;

  // ------- global scratch layout -------
  // floats: PA[4096], PB[4096]
  // u64   : hpub[128*8] ppub[1296] pubD/F/H/J[128*8 each] wEF..rPL[128 each]
  float* ws = P.ws;
  float* PA = ws;
  float* PB = ws + 4096;
  unsigned long long* U    = (unsigned long long*)(ws + 8192);
  unsigned long long* hpub = U;                 // 1024
  unsigned long long* ppub = U + 1024;          // 1296
  unsigned long long* pubD = U + 2320;          // 1024
  unsigned long long* pubF = pubD + 1024;
  unsigned long long* pubH = pubF + 1024;
  unsigned long long* pubJ = pubH + 1024;
  unsigned long long* wEF = pubJ + 1024;
  unsigned long long* wPF = wEF + 128;
  unsigned long long* wEL = wPF + 128;
  unsigned long long* wPL = wEL + 128;
  unsigned long long* rEF = wPL + 128;
  unsigned long long* rPF = rEF + 128;
  unsigned long long* rEL = rPF + 128;
  unsigned long long* rPL = rEL + 128;
  float* Pbuf[2] = { PA, PB };

  // ------- LDS -------
  __shared__ float s_mem[RPB * Dsz];   // 128KB
  __shared__ float s_co[Hsz];
  __shared__ float s_a[256], s_b[256], s_c[256];
  __shared__ float s_rv[256];
  __shared__ float s_norm[RPB];
  __shared__ float s_e[RPB];
  __shared__ float s_bw[RPB];
  __shared__ float s_rw[RPB];
  __shared__ float s_ww[RPB];
  __shared__ float s_A1[RPB], s_A2[RPB], s_B1[RPB], s_B0[RPB];
  __shared__ float s_red[8];
  __shared__ float s_lg[16];
  __shared__ float s_scal[16];
  __shared__ float s_wsum[8];
  __shared__ float s_w2[2];
  __shared__ float s_cst[4];
  __shared__ float s_bd[4];
  __shared__ float s_pub;
  __shared__ float s_gval;

  // arrival-word sum-barrier wait: polls all 128 tagged arrivals, sums payloads
  auto pubWaitSum = [&](unsigned long long* pub, unsigned want)->float{
    if (wv == 0){
      const unsigned long long* p0 = &pub[(size_t)ln * PUBSTR];
      const unsigned long long* p1 = &pub[(size_t)(64 + ln) * PUBSTR];
      unsigned long long k0, k1;
      for (;;){
        k0 = gload64(p0); k1 = gload64(p1);
        bool ok = ((int)((unsigned)(k0 >> 32) - want) >= 0) &&
                  ((int)((unsigned)(k1 >> 32) - want) >= 0);
        if (__all(ok)) break;
      }
      float acc = __uint_as_float((unsigned)k0) + __uint_as_float((unsigned)k1);
      acc = wred64(acc);
      if (ln == 0) s_gval = acc;
    }
    lbar();
    return s_gval;
  };

  auto bred512 = [&](float v)->float{
    v = wred64(v);
    lbar();
    if (ln == 0) s_red[wv] = v;
    lbar();
    return s_red[0] + s_red[1] + s_red[2] + s_red[3]
         + s_red[4] + s_red[5] + s_red[6] + s_red[7];
  };

  // shift + sharpen; boundaries from s_bd; block partial -> s_pub (and pub if given)
  auto shiftSharpen = [&](int si, float* s_prevw, float S,
                          unsigned long long* pub, unsigned tag){
    float g     = sigm(s_scal[si + 1]);
    float gamma = softplusf(s_scal[si + 2]) + 1.f;
    float a0 = s_scal[si + 3], a1 = s_scal[si + 4], a2 = s_scal[si + 5];
    float mx = fmaxf(a0, fmaxf(a1, a2));
    float e0 = __expf(a0 - mx), e1 = __expf(a1 - mx), e2 = __expf(a2 - mx);
    float idn = 1.f / (e0 + e1 + e2);
    float s0 = e0 * idn, s1 = e1 * idn, s2 = e2 * idn;
    float invS = 1.f / S;
    float w = 0.f;
    if (tid < RPB){
      float gc = g * invS, gp = 1.f - g;
      float em = s_e[tid],  pm = s_prevw[tid];
      float e1n = (tid < RPB-1) ? s_e[tid+1]     : s_bd[0];
      float p1n = (tid < RPB-1) ? s_prevw[tid+1] : s_bd[1];
      float e2n = (tid > 0)     ? s_e[tid-1]     : s_bd[2];
      float p2n = (tid > 0)     ? s_prevw[tid-1] : s_bd[3];
      float gwm = gc * em  + gp * pm;
      float gw1 = gc * e1n + gp * p1n;   // roll(gw,-1)
      float gw2 = gc * e2n + gp * p2n;   // roll(gw,+1)
      float sh = s0 * gw1 + s1 * gwm + s2 * gw2;
      w = powf(sh, gamma);
      s_bw[tid] = w;
    }
    float tot = wred64(w);
    if (ln == 0 && wv < 2) s_w2[wv] = tot;
    lbar();
    if (tid == 0){
      float T2 = s_w2[0] + s_w2[1];
      s_pub = T2;
      if (pub) gstore64(&pub[(size_t)b * PUBSTR],
                        ((unsigned long long)tag << 32) | (unsigned long long)__float_as_uint(T2));
    }
  };

  // LSTM GEMV, x-part (s_a) + h-part (s_co); rvec part added later in A
  auto gemvXH = [&]()->float{
    int dd = tid >> 5, l = tid & 31;
    int r = (dd >> 2) * Hsz + (b << 2) + (dd & 3);
    const float* wi = W_ih + (size_t)r * (Isz + Dsz);
    const float* wh = W_hh + (size_t)r * Hsz;
    float acc = 0.f;
#pragma unroll
    for (int it = 0; it < 2; ++it){
      int k = it * 128 + l * 4;
      float4 a = *(const float4*)(wi + k);
      float4 x = *(const float4*)(&s_a[k]);
      acc += a.x*x.x + a.y*x.y + a.z*x.z + a.w*x.w;
    }
#pragma unroll
    for (int it = 0; it < 4; ++it){
      int k = it * 128 + l * 4;
      float4 hw = *(const float4*)(wh + k);
      float4 hv = *(const float4*)(&s_co[k]);
      acc += hw.x*hv.x + hw.y*hv.y + hw.z*hv.z + hw.w*hv.w;
    }
    return acc;
  };

  float Srcarry = 1.f;
  float accxh   = 0.f;

  // ------- INIT1: zero parts; load initial weights/state; s_co=0 (tag 1) -------
  {
    if (b < NG && tid < 256){ gstore(&PA[b*256 + tid], 0.f); gstore(&PB[b*256 + tid], 0.f); }
    if (tid < RPB){
      s_rw[tid] = read_w0[b * RPB + tid];
      s_ww[tid] = write_w0[b * RPB + tid];
    }
    if (tid < 4) s_cst[tid] = 0.f;
    s_co[tid] = 0.f;
    __syncthreads();                               // drain zero stores
    if (tid == 0) gstore64(&pubD[(size_t)b * PUBSTR], (1ull << 32));
    pubWaitSum(pubD, 1);
  }

  // ------- INIT2: memory -> LDS, norms, initial rvec partials (tag 2) -------
  {
#pragma unroll 1
    for (int it = 0; it < 16; ++it){
      int ml = it * 8 + wv;
      int m  = b * RPB + ml;
      float4 v = *(const float4*)(mem0 + (size_t)m * Dsz + ln * 4);
      *(float4*)(&s_mem[ml * Dsz + ln * 4]) = v;
      float n2 = wred64(v.x*v.x + v.y*v.y + v.z*v.z + v.w*v.w);
      if (ln == 0) s_norm[ml] = sqrtf(n2);
    }
    lbar();
    int col = tid & 255, half = tid >> 8;
    float acc = 0.f;
#pragma unroll 1
    for (int j = half * 64; j < half * 64 + 64; ++j) acc += s_rw[j] * s_mem[j * Dsz + col];
    if (half == 0) s_a[col] = acc;
    lbar();
    if (half == 1) atomicAdd(&PB[(b & (NG-1)) * 256 + col], acc + s_a[col]);
    __syncthreads();                               // drain atomics
    if (tid < 256) s_a[tid] = inputs[tid];         // stage x(0)
    if (tid == 0) gstore64(&pubD[(size_t)b * PUBSTR], (2ull << 32));
    lbar();
    accxh = gemvXH();                              // h = 0 -> W_hh part is 0
    pubWaitSum(pubD, 2);
  }

  // =================== time loop ===================
  for (int t = 0; t < Tlen; ++t){
    const unsigned TT = (unsigned)(t + 3);
    const unsigned long long tg = (unsigned long long)TT << 32;
    float* Pcur = Pbuf[t & 1];          // J(t) atomics
    float* Prd  = Pbuf[(t + 1) & 1];    // A(t) reads

    // ---- A: deferred rw/rvec normalize; finish LSTM; publish tagged h ----
    {
      float SrDiv = (t == 0) ? 1.f : (Srcarry + 1e-8f);
      if (t > 0 && tid < RPB) s_rw[tid] = s_bw[tid] / SrDiv;
      if (tid < 256){
        float rvv = 0.f;
#pragma unroll
        for (int p = 0; p < NG; ++p) rvv += gload(&Prd[p * 256 + tid]);
        s_rv[tid] = rvv / SrDiv;
      }
      lbar();
      int dd = tid >> 5, l = tid & 31;
      int r = (dd >> 2) * Hsz + (b << 2) + (dd & 3);
      const float* wi = W_ih + (size_t)r * (Isz + Dsz) + Isz;
      float acc = accxh;
#pragma unroll
      for (int it = 0; it < 2; ++it){
        int k = it * 128 + l * 4;
        float4 a = *(const float4*)(wi + k);
        float4 x = *(const float4*)(&s_rv[k]);
        acc += a.x*x.x + a.y*x.y + a.z*x.z + a.w*x.w;
      }
      acc = wred32(acc);
      if (l == 0) s_lg[dd] = acc + b_ih[r] + b_hh[r];
      lbar();
      if (tid < 4){
        float iv = s_lg[tid], fv = s_lg[4 + tid], gv = s_lg[8 + tid], ov = s_lg[12 + tid];
        float cn = sigm(fv) * s_cst[tid] + sigm(iv) * tanhf(gv);
        s_cst[tid] = cn;
        float hn = sigm(ov) * tanhf(cn);
        gstore64(&hpub[(size_t)b * 8 + tid], tg | (unsigned long long)__float_as_uint(hn));
      }
    }

    // ---- C: poll tagged h; projections -> tagged slot words / out ----
    {
      s_co[tid] = pollw(&hpub[(size_t)(tid >> 2) * 8 + (tid & 3)], TT);
      lbar();
#pragma unroll
      for (int qi = 0; qi < 2; ++qi){
        int q = qi * 8 + wv;          // 0..15
        int slot = q * 128 + b;
        if (slot < 1292){
          const float* Wrow = nullptr; float bias = 0.f; int len = 512;
          int mode = 0;  // 0: tagged pub, 1: sigmoid + pub, 2: out store
          if (slot < 256){ Wrow = w_Wk + (size_t)slot * Hsz; bias = w_bk[slot]; }
          else if (slot < 512){ int i = slot - 256; Wrow = w_We + (size_t)i * Hsz; bias = w_be[i]; mode = 1; }
          else if (slot < 768){ int i = slot - 512; Wrow = w_Wa + (size_t)i * Hsz; bias = w_ba[i]; }
          else if (slot < 1024){ int i = slot - 768; Wrow = r_Wk + (size_t)i * Hsz; bias = r_bk[i]; }
          else if (slot < 1280){ int i = slot - 1024; Wrow = Wo + (size_t)i * (Hsz + Dsz); bias = bo[i]; len = 768; mode = 2; }
          else {
            int i = slot - 1280;
            int ii = (i >= 6) ? i - 6 : i;
            bool rh = (i >= 6);
            const float *Wt, *bt; int row = 0;
            if (ii == 0){ Wt = rh ? r_Wb : w_Wb; bt = rh ? r_bb : w_bb; }
            else if (ii == 1){ Wt = rh ? r_Wg : w_Wg; bt = rh ? r_bg : w_bg; }
            else if (ii == 2){ Wt = rh ? r_Wp : w_Wp; bt = rh ? r_bp : w_bp; }
            else { Wt = rh ? r_Ws : w_Ws; bt = rh ? r_bs : w_bs; row = ii - 3; }
            Wrow = Wt + (size_t)row * Hsz; bias = bt[row];
          }
          float acc = 0.f;
          if (len == 512){
            int k = ln * 8;
            float4 a0 = *(const float4*)(Wrow + k);
            float4 a1 = *(const float4*)(Wrow + k + 4);
            float4 c0 = *(const float4*)(&s_co[k]);
            float4 c1 = *(const float4*)(&s_co[k + 4]);
            acc = a0.x*c0.x + a0.y*c0.y + a0.z*c0.z + a0.w*c0.w
                + a1.x*c1.x + a1.y*c1.y + a1.z*c1.z + a1.w*c1.w;
          } else {
#pragma unroll 1
            for (int kk = ln; kk < 768; kk += 64){
              float xv = (kk < Hsz) ? s_co[kk] : s_rv[kk - Hsz];
              acc += Wrow[kk] * xv;
            }
          }
          acc = wred64(acc);
          if (ln == 0){
            float v = acc + bias;
            if (mode == 1) v = sigm(v);
            if (mode == 2) out[(size_t)t * Isz + (slot - 1024)] = v;
            else gstore64(&ppub[slot], tg | (unsigned long long)__float_as_uint(v));
          }
        }
      }
    }

    if (t == Tlen - 1) break;   // out(127) done; D..J only produce next-step state

    float betaR = 0.f, invbkR = 0.f;
    float4 er4, ad4, kr4;

    // ---- D: poll keyw+scal; write-head content scores; publish S_w partial ----
    {
      float* Pnx = Pbuf[(t + 1) & 1];
      if (b < NG && tid < 256) gstore(&Pnx[b * 256 + tid], 0.f);
      if (tid < 256) s_a[tid] = pollw(&ppub[tid], TT);
      else if (tid < 268) s_scal[tid - 256] = pollw(&ppub[1280 + (tid - 256)], TT);
      lbar();
      float nk2 = bred512((tid < 256) ? s_a[tid] * s_a[tid] : 0.f);
      float beta  = softplusf(s_scal[0]);
      float invbk = beta / fmaxf(sqrtf(nk2), 1e-12f);
      float esum = 0.f;
#pragma unroll 1
      for (int it = 0; it < 16; ++it){
        int ml = it * 8 + wv;
        float4 v  = *(const float4*)(&s_mem[ml * Dsz + ln * 4]);
        float4 kv = *(const float4*)(&s_a[ln * 4]);
        float d = wred64(v.x*kv.x + v.y*kv.y + v.z*kv.z + v.w*kv.w);
        float score = d * invbk / fmaxf(s_norm[ml], 1e-12f);
        float e = __expf(score - beta);
        if (ln == 0){ s_e[ml] = e; esum += e; }
      }
      if (ln == 0) s_wsum[wv] = esum;
      lbar();
      if (tid == 0){
        float tot = 0.f;
#pragma unroll
        for (int k = 0; k < 8; ++k) tot += s_wsum[k];
        gstore64(&wEF[b], tg | (unsigned long long)__float_as_uint(s_e[0]));
        gstore64(&wPF[b], tg | (unsigned long long)__float_as_uint(s_ww[0]));
        gstore64(&wEL[b], tg | (unsigned long long)__float_as_uint(s_e[RPB-1]));
        gstore64(&wPL[b], tg | (unsigned long long)__float_as_uint(s_ww[RPB-1]));
        gstore64(&pubD[(size_t)b * PUBSTR], tg | (unsigned long long)__float_as_uint(tot));
      }
    }

    // ---- H-pre: poll er/ad/kr; Sw-independent reductions (hides S_w wait) ----
    // mem_new = mv + ww*q, q = ad - mv*er  =>
    //   |mem_new|^2   = A0 + ww*A1 + ww^2*A2   (A0 = norm^2, A1 = 2<mv,q>, A2 = |q|^2)
    //   <mem_new,kr>  = B0 + ww*B1            (B0 = <mv,kr>, B1 = <q,kr>)
    {
      if (tid < 256) s_a[tid] = pollw(&ppub[256 + tid], TT);          // erase (sigmoided)
      else           s_b[tid - 256] = pollw(&ppub[512 + (tid - 256)], TT);  // add
      if (tid < 256) s_c[tid] = pollw(&ppub[768 + tid], TT);          // keyr
      float nk2r = bred512((tid < 256) ? s_c[tid] * s_c[tid] : 0.f);
      betaR  = softplusf(s_scal[6]);
      invbkR = betaR / fmaxf(sqrtf(nk2r), 1e-12f);
      er4 = *(const float4*)(&s_a[ln * 4]);
      ad4 = *(const float4*)(&s_b[ln * 4]);
      kr4 = *(const float4*)(&s_c[ln * 4]);
#pragma unroll 1
      for (int it = 0; it < 16; ++it){
        int ml = it * 8 + wv;
        float4 mv = *(const float4*)(&s_mem[ml * Dsz + ln * 4]);
        float4 q;
        q.x = ad4.x - mv.x * er4.x;
        q.y = ad4.y - mv.y * er4.y;
        q.z = ad4.z - mv.z * er4.z;
        q.w = ad4.w - mv.w * er4.w;
        float mq = mv.x*q.x + mv.y*q.y + mv.z*q.z + mv.w*q.w;
        float qq = q.x*q.x + q.y*q.y + q.z*q.z + q.w*q.w;
        float qk = q.x*kr4.x + q.y*kr4.y + q.z*kr4.z + q.w*kr4.w;
        float mk = mv.x*kr4.x + mv.y*kr4.y + mv.z*kr4.z + mv.w*kr4.w;
        mq = wred64(mq); qq = wred64(qq); qk = wred64(qk); mk = wred64(mk);
        if (ln == 0){ s_A1[ml] = 2.f*mq; s_A2[ml] = qq; s_B1[ml] = qk; s_B0[ml] = mk; }
      }
    }

    // ---- F: write-head shift+sharpen (S_w should already be there) ----
    {
      if (wv == 0 && ln < 4){
        const unsigned long long* bp = (ln == 0) ? &wEF[(b + 1) & (NBLK-1)]
                               : (ln == 1) ? &wPF[(b + 1) & (NBLK-1)]
                               : (ln == 2) ? &wEL[(b - 1) & (NBLK-1)]
                                           : &wPL[(b - 1) & (NBLK-1)];
        s_bd[ln] = pollw(bp, TT);
      }
      float S_w = pubWaitSum(pubD, TT);
      shiftSharpen(0, s_ww, S_w, pubF, TT);
    }

    // ---- H-post: wait Sw; cheap elementwise mem update + per-row fixups ----
    {
      float Sw = pubWaitSum(pubF, TT);
      float invSw = 1.f / (Sw + 1e-8f);
#pragma unroll 1
      for (int it = 0; it < 16; ++it){
        int ml = it * 8 + wv;
        int off = ml * Dsz + ln * 4;
        float wwm = s_bw[ml] * invSw;
        float4 mv = *(const float4*)(&s_mem[off]);
        float4 nv;
        nv.x = fmaf(wwm, ad4.x - mv.x * er4.x, mv.x);
        nv.y = fmaf(wwm, ad4.y - mv.y * er4.y, mv.y);
        nv.z = fmaf(wwm, ad4.z - mv.z * er4.z, mv.z);
        nv.w = fmaf(wwm, ad4.w - mv.w * er4.w, mv.w);
        *(float4*)(&s_mem[off]) = nv;
      }
      float e = 0.f;
      if (tid < RPB){
        float wwm = s_bw[tid] * invSw;
        s_ww[tid] = wwm;
        float A0 = s_norm[tid] * s_norm[tid];
        float n2 = fmaf(wwm, fmaf(wwm, s_A2[tid], s_A1[tid]), A0);
        float dt = fmaf(wwm, s_B1[tid], s_B0[tid]);
        float nr = sqrtf(fmaxf(n2, 0.f));
        s_norm[tid] = nr;
        float score = dt * invbkR / fmaxf(nr, 1e-12f);
        e = __expf(score - betaR);
        s_e[tid] = e;
      }
      float tot = wred64(e);
      if (ln == 0 && wv < 2) s_w2[wv] = tot;
      lbar();
      if (tid == 0){
        float T2 = s_w2[0] + s_w2[1];
        gstore64(&rEF[b], tg | (unsigned long long)__float_as_uint(s_e[0]));
        gstore64(&rPF[b], tg | (unsigned long long)__float_as_uint(s_rw[0]));
        gstore64(&rEL[b], tg | (unsigned long long)__float_as_uint(s_e[RPB-1]));
        gstore64(&rPL[b], tg | (unsigned long long)__float_as_uint(s_rw[RPB-1]));
        gstore64(&pubH[(size_t)b * PUBSTR], tg | (unsigned long long)__float_as_uint(T2));
      }
    }

    // ---- J: read sharpen; rvec partials; next-step GEMV hides pubJ wait ----
    {
      if (wv == 0 && ln < 4){
        const unsigned long long* bp = (ln == 0) ? &rEF[(b + 1) & (NBLK-1)]
                               : (ln == 1) ? &rPF[(b + 1) & (NBLK-1)]
                               : (ln == 2) ? &rEL[(b - 1) & (NBLK-1)]
                                           : &rPL[(b - 1) & (NBLK-1)];
        s_bd[ln] = pollw(bp, TT);
      }
      float S_r = pubWaitSum(pubH, TT);
      shiftSharpen(6, s_rw, S_r, nullptr, 0);   // partial left in s_pub
      lbar();
      int col = tid & 255, half = tid >> 8;
      float acc = 0.f;
#pragma unroll 1
      for (int j = half * 64; j < half * 64 + 64; ++j) acc += s_bw[j] * s_mem[j * Dsz + col];
      if (half == 0) s_a[col] = acc;
      lbar();
      if (half == 1) atomicAdd(&Pcur[(b & (NG-1)) * 256 + col], acc + s_a[col]);
      __syncthreads();                           // drain atomics (and D's zeroes)
      if (tid == 0)
        gstore64(&pubJ[(size_t)b * PUBSTR], tg | (unsigned long long)__float_as_uint(s_pub));
      // hide the pubJ wait under next step's x/h GEMV parts
      if (tid < 256) s_a[tid] = inputs[(size_t)(t + 1) * Isz + tid];
      lbar();
      accxh = gemvXH();
      Srcarry = pubWaitSum(pubJ, TT);
    }
  }
}

extern "C" void kernel_launch(void* const* d_in, const int* in_sizes, int n_in,
                              void* d_out, int out_size, void* d_ws, size_t ws_size,
                              hipStream_t stream)
{
  (void)in_sizes; (void)out_size;
  if (n_in < 34) return;
  if (ws_size < (size_t)98304) return;   // ~92KB scratch needed
  Params P;
  for (int i = 0; i < 34; ++i) P.in[i] = (const float*)d_in[i];
  P.out = (float*)d_out;
  P.ws  = (float*)d_ws;
  hipLaunchKernelGGL(ntm_kernel, dim3(NBLK), dim3(NTHR), 0, stream, P);
}

// Round 2
// 3664.348 us; speedup vs baseline: 1.3873x; 1.3873x over previous
//
#include <hip/hip_runtime.h>
#include <math.h>

// Persistent-kernel NTM, R13: quad-per-row DPP reductions in D and H-pre.
// R12's tagged-dataflow structure kept identical; the 64 wred64/step that
// R12's H-pre added (51M LDS bank-conflict cycles) are replaced by
// 4-lane DPP quad reduces (VALU pipe, no DS ops). Chunk rotation (k+row)&15
// spreads s_mem reads across all 32 banks.

#define NBLK 128
#define NTHR 512
#define Msz  16384
#define Dsz  256
#define Hsz  512
#define Isz  256
#define Tlen 128
#define RPB  128
#define NG   16
#define PUBSTR 8   // u64 stride (64B) for arrival arrays

struct Params { const float* in[34]; float* out; float* ws; };

__device__ __forceinline__ float wred64(float v){
#pragma unroll
  for (int o = 32; o > 0; o >>= 1) v += __shfl_xor(v, o, 64);
  return v;
}
__device__ __forceinline__ float wred32(float v){
#pragma unroll
  for (int o = 16; o > 0; o >>= 1) v += __shfl_xor(v, o, 32);
  return v;
}
// sum over each 4-lane quad via DPP quad_perm (no DS ops, no bank conflicts)
__device__ __forceinline__ float qsum4(float v){
  v += __uint_as_float(__builtin_amdgcn_mov_dpp(__float_as_uint(v), 0xB1, 0xF, 0xF, true)); // xor1
  v += __uint_as_float(__builtin_amdgcn_mov_dpp(__float_as_uint(v), 0x4E, 0xF, 0xF, true)); // xor2
  return v;
}
__device__ __forceinline__ float sigm(float x){ return 1.f / (1.f + __expf(-x)); }
__device__ __forceinline__ float softplusf(float x){ return (x > 20.f) ? x : log1pf(__expf(x)); }

__device__ __forceinline__ void gstore(float* p, float v){
  __hip_atomic_store(p, v, __ATOMIC_RELAXED, __HIP_MEMORY_SCOPE_AGENT);
}
__device__ __forceinline__ float gload(const float* p){
  return __hip_atomic_load(p, __ATOMIC_RELAXED, __HIP_MEMORY_SCOPE_AGENT);
}
__device__ __forceinline__ void gstore64(unsigned long long* p, unsigned long long v){
  __hip_atomic_store(p, v, __ATOMIC_RELAXED, __HIP_MEMORY_SCOPE_AGENT);
}
__device__ __forceinline__ unsigned long long gload64(const unsigned long long* p){
  return __hip_atomic_load(p, __ATOMIC_RELAXED, __HIP_MEMORY_SCOPE_AGENT);
}
// lgkmcnt(0)-only barrier: vmcnt=63, expcnt=7, lgkmcnt=0 -> imm 0xC07F
__device__ __forceinline__ void lbar(){
  __builtin_amdgcn_s_waitcnt(0xC07F);
  __builtin_amdgcn_s_barrier();
}
// poll a tagged word until tag >= want; return payload float
__device__ __forceinline__ float pollw(const unsigned long long* p, unsigned want){
  unsigned long long k;
  do { k = gload64(p); } while ((int)((unsigned)(k >> 32) - want) < 0);
  return __uint_as_float((unsigned)k);
}

__global__ void __launch_bounds__(NTHR, 1)
ntm_kernel(Params P)
{
  const int b   = blockIdx.x;
  const int tid = threadIdx.x;
  const int wv  = tid >> 6;   // wave 0..7
  const int ln  = tid & 63;

  // ------- inputs (setup_inputs dict order) -------
  const float* inputs  = P.in[0];
  const float* mem0    = P.in[1];
  const float* read_w0 = P.in[2];
  const float* write_w0= P.in[3];
  const float* W_ih = P.in[4];
  const float* W_hh = P.in[5];
  const float* b_ih = P.in[6];
  const float* b_hh = P.in[7];
  const float* Wo   = P.in[8];
  const float* bo   = P.in[9];
  const float* r_Wk = P.in[10]; const float* r_bk = P.in[11];
  const float* r_Wb = P.in[12]; const float* r_bb = P.in[13];
  const float* r_Wg = P.in[14]; const float* r_bg = P.in[15];
  const float* r_Ws = P.in[16]; const float* r_bs = P.in[17];
  const float* r_Wp = P.in[18]; const float* r_bp = P.in[19];
  const float* w_Wk = P.in[20]; const float* w_bk = P.in[21];
  const float* w_Wb = P.in[22]; const float* w_bb = P.in[23];
  const float* w_Wg = P.in[24]; const float* w_bg = P.in[25];
  const float* w_Ws = P.in[26]; const float* w_bs = P.in[27];
  const float* w_Wp = P.in[28]; const float* w_bp = P.in[29];
  const float* w_We = P.in[30]; const float* w_be = P.in[31];
  const float* w_Wa = P.in[32]; const float* w_ba = P.in[33];
  float* out = P.out;

  // ------- global scratch layout -------
  float* ws = P.ws;
  float* PA = ws;
  float* PB = ws + 4096;
  unsigned long long* U    = (unsigned long long*)(ws + 8192);
  unsigned long long* hpub = U;                 // 1024
  unsigned long long* ppub = U + 1024;          // 1296
  unsigned long long* pubD = U + 2320;          // 1024
  unsigned long long* pubF = pubD + 1024;
  unsigned long long* pubH = pubF + 1024;
  unsigned long long* pubJ = pubH + 1024;
  unsigned long long* wEF = pubJ + 1024;
  unsigned long long* wPF = wEF + 128;
  unsigned long long* wEL = wPF + 128;
  unsigned long long* wPL = wEL + 128;
  unsigned long long* rEF = wPL + 128;
  unsigned long long* rPF = rEF + 128;
  unsigned long long* rEL = rPF + 128;
  unsigned long long* rPL = rEL + 128;
  float* Pbuf[2] = { PA, PB };

  // ------- LDS -------
  __shared__ float s_mem[RPB * Dsz];   // 128KB
  __shared__ float s_co[Hsz];
  __shared__ float s_a[256], s_b[256], s_c[256];
  __shared__ float s_rv[256];
  __shared__ float s_norm[RPB];
  __shared__ float s_e[RPB];
  __shared__ float s_bw[RPB];
  __shared__ float s_rw[RPB];
  __shared__ float s_ww[RPB];
  __shared__ float s_A1[RPB], s_A2[RPB], s_B1[RPB], s_B0[RPB];
  __shared__ float s_dot[RPB];
  __shared__ float s_red[8];
  __shared__ float s_lg[16];
  __shared__ float s_scal[16];
  __shared__ float s_w2[2];
  __shared__ float s_cst[4];
  __shared__ float s_bd[4];
  __shared__ float s_pub;
  __shared__ float s_gval;

  // arrival-word sum-barrier wait: polls all 128 tagged arrivals, sums payloads
  auto pubWaitSum = [&](unsigned long long* pub, unsigned want)->float{
    if (wv == 0){
      const unsigned long long* p0 = &pub[(size_t)ln * PUBSTR];
      const unsigned long long* p1 = &pub[(size_t)(64 + ln) * PUBSTR];
      unsigned long long k0, k1;
      for (;;){
        k0 = gload64(p0); k1 = gload64(p1);
        bool ok = ((int)((unsigned)(k0 >> 32) - want) >= 0) &&
                  ((int)((unsigned)(k1 >> 32) - want) >= 0);
        if (__all(ok)) break;
      }
      float acc = __uint_as_float((unsigned)k0) + __uint_as_float((unsigned)k1);
      acc = wred64(acc);
      if (ln == 0) s_gval = acc;
    }
    lbar();
    return s_gval;
  };

  auto bred512 = [&](float v)->float{
    v = wred64(v);
    lbar();
    if (ln == 0) s_red[wv] = v;
    lbar();
    return s_red[0] + s_red[1] + s_red[2] + s_red[3]
         + s_red[4] + s_red[5] + s_red[6] + s_red[7];
  };

  // shift + sharpen; boundaries from s_bd; block partial -> s_pub (and pub if given)
  auto shiftSharpen = [&](int si, float* s_prevw, float S,
                          unsigned long long* pub, unsigned tag){
    float g     = sigm(s_scal[si + 1]);
    float gamma = softplusf(s_scal[si + 2]) + 1.f;
    float a0 = s_scal[si + 3], a1 = s_scal[si + 4], a2 = s_scal[si + 5];
    float mx = fmaxf(a0, fmaxf(a1, a2));
    float e0 = __expf(a0 - mx), e1 = __expf(a1 - mx), e2 = __expf(a2 - mx);
    float idn = 1.f / (e0 + e1 + e2);
    float s0 = e0 * idn, s1 = e1 * idn, s2 = e2 * idn;
    float invS = 1.f / S;
    float w = 0.f;
    if (tid < RPB){
      float gc = g * invS, gp = 1.f - g;
      float em = s_e[tid],  pm = s_prevw[tid];
      float e1n = (tid < RPB-1) ? s_e[tid+1]     : s_bd[0];
      float p1n = (tid < RPB-1) ? s_prevw[tid+1] : s_bd[1];
      float e2n = (tid > 0)     ? s_e[tid-1]     : s_bd[2];
      float p2n = (tid > 0)     ? s_prevw[tid-1] : s_bd[3];
      float gwm = gc * em  + gp * pm;
      float gw1 = gc * e1n + gp * p1n;   // roll(gw,-1)
      float gw2 = gc * e2n + gp * p2n;   // roll(gw,+1)
      float sh = s0 * gw1 + s1 * gwm + s2 * gw2;
      w = powf(sh, gamma);
      s_bw[tid] = w;
    }
    float tot = wred64(w);
    if (ln == 0 && wv < 2) s_w2[wv] = tot;
    lbar();
    if (tid == 0){
      float T2 = s_w2[0] + s_w2[1];
      s_pub = T2;
      if (pub) gstore64(&pub[(size_t)b * PUBSTR],
                        ((unsigned long long)tag << 32) | (unsigned long long)__float_as_uint(T2));
    }
  };

  // LSTM GEMV, x-part (s_a) + h-part (s_co); rvec part added later in A
  auto gemvXH = [&]()->float{
    int dd = tid >> 5, l = tid & 31;
    int r = (dd >> 2) * Hsz + (b << 2) + (dd & 3);
    const float* wi = W_ih + (size_t)r * (Isz + Dsz);
    const float* wh = W_hh + (size_t)r * Hsz;
    float acc = 0.f;
#pragma unroll
    for (int it = 0; it < 2; ++it){
      int k = it * 128 + l * 4;
      float4 a = *(const float4*)(wi + k);
      float4 x = *(const float4*)(&s_a[k]);
      acc += a.x*x.x + a.y*x.y + a.z*x.z + a.w*x.w;
    }
#pragma unroll
    for (int it = 0; it < 4; ++it){
      int k = it * 128 + l * 4;
      float4 hw = *(const float4*)(wh + k);
      float4 hv = *(const float4*)(&s_co[k]);
      acc += hw.x*hv.x + hw.y*hv.y + hw.z*hv.z + hw.w*hv.w;
    }
    return acc;
  };

  float Srcarry = 1.f;
  float accxh   = 0.f;

  // ------- INIT1: zero parts; load initial weights/state; s_co=0 (tag 1) -------
  {
    if (b < NG && tid < 256){ gstore(&PA[b*256 + tid], 0.f); gstore(&PB[b*256 + tid], 0.f); }
    if (tid < RPB){
      s_rw[tid] = read_w0[b * RPB + tid];
      s_ww[tid] = write_w0[b * RPB + tid];
    }
    if (tid < 4) s_cst[tid] = 0.f;
    s_co[tid] = 0.f;
    __syncthreads();                               // drain zero stores
    if (tid == 0) gstore64(&pubD[(size_t)b * PUBSTR], (1ull << 32));
    pubWaitSum(pubD, 1);
  }

  // ------- INIT2: memory -> LDS, norms, initial rvec partials (tag 2) -------
  {
#pragma unroll 1
    for (int it = 0; it < 16; ++it){
      int ml = it * 8 + wv;
      int m  = b * RPB + ml;
      float4 v = *(const float4*)(mem0 + (size_t)m * Dsz + ln * 4);
      *(float4*)(&s_mem[ml * Dsz + ln * 4]) = v;
      float n2 = wred64(v.x*v.x + v.y*v.y + v.z*v.z + v.w*v.w);
      if (ln == 0) s_norm[ml] = sqrtf(n2);
    }
    lbar();
    int col = tid & 255, half = tid >> 8;
    float acc = 0.f;
#pragma unroll 1
    for (int j = half * 64; j < half * 64 + 64; ++j) acc += s_rw[j] * s_mem[j * Dsz + col];
    if (half == 0) s_a[col] = acc;
    lbar();
    if (half == 1) atomicAdd(&PB[(b & (NG-1)) * 256 + col], acc + s_a[col]);
    __syncthreads();                               // drain atomics
    if (tid < 256) s_a[tid] = inputs[tid];         // stage x(0)
    if (tid == 0) gstore64(&pubD[(size_t)b * PUBSTR], (2ull << 32));
    lbar();
    accxh = gemvXH();                              // h = 0 -> W_hh part is 0
    pubWaitSum(pubD, 2);
  }

  // =================== time loop ===================
  for (int t = 0; t < Tlen; ++t){
    const unsigned TT = (unsigned)(t + 3);
    const unsigned long long tg = (unsigned long long)TT << 32;
    float* Pcur = Pbuf[t & 1];          // J(t) atomics
    float* Prd  = Pbuf[(t + 1) & 1];    // A(t) reads

    // ---- A: deferred rw/rvec normalize; finish LSTM; publish tagged h ----
    {
      float SrDiv = (t == 0) ? 1.f : (Srcarry + 1e-8f);
      if (t > 0 && tid < RPB) s_rw[tid] = s_bw[tid] / SrDiv;
      if (tid < 256){
        float rvv = 0.f;
#pragma unroll
        for (int p = 0; p < NG; ++p) rvv += gload(&Prd[p * 256 + tid]);
        s_rv[tid] = rvv / SrDiv;
      }
      lbar();
      int dd = tid >> 5, l = tid & 31;
      int r = (dd >> 2) * Hsz + (b << 2) + (dd & 3);
      const float* wi = W_ih + (size_t)r * (Isz + Dsz) + Isz;
      float acc = accxh;
#pragma unroll
      for (int it = 0; it < 2; ++it){
        int k = it * 128 + l * 4;
        float4 a = *(const float4*)(wi + k);
        float4 x = *(const float4*)(&s_rv[k]);
        acc += a.x*x.x + a.y*x.y + a.z*x.z + a.w*x.w;
      }
      acc = wred32(acc);
      if (l == 0) s_lg[dd] = acc + b_ih[r] + b_hh[r];
      lbar();
      if (tid < 4){
        float iv = s_lg[tid], fv = s_lg[4 + tid], gv = s_lg[8 + tid], ov = s_lg[12 + tid];
        float cn = sigm(fv) * s_cst[tid] + sigm(iv) * tanhf(gv);
        s_cst[tid] = cn;
        float hn = sigm(ov) * tanhf(cn);
        gstore64(&hpub[(size_t)b * 8 + tid], tg | (unsigned long long)__float_as_uint(hn));
      }
    }

    // ---- C: poll tagged h; projections -> tagged slot words / out ----
    {
      s_co[tid] = pollw(&hpub[(size_t)(tid >> 2) * 8 + (tid & 3)], TT);
      lbar();
#pragma unroll
      for (int qi = 0; qi < 2; ++qi){
        int q = qi * 8 + wv;          // 0..15
        int slot = q * 128 + b;
        if (slot < 1292){
          const float* Wrow = nullptr; float bias = 0.f; int len = 512;
          int mode = 0;  // 0: tagged pub, 1: sigmoid + pub, 2: out store
          if (slot < 256){ Wrow = w_Wk + (size_t)slot * Hsz; bias = w_bk[slot]; }
          else if (slot < 512){ int i = slot - 256; Wrow = w_We + (size_t)i * Hsz; bias = w_be[i]; mode = 1; }
          else if (slot < 768){ int i = slot - 512; Wrow = w_Wa + (size_t)i * Hsz; bias = w_ba[i]; }
          else if (slot < 1024){ int i = slot - 768; Wrow = r_Wk + (size_t)i * Hsz; bias = r_bk[i]; }
          else if (slot < 1280){ int i = slot - 1024; Wrow = Wo + (size_t)i * (Hsz + Dsz); bias = bo[i]; len = 768; mode = 2; }
          else {
            int i = slot - 1280;
            int ii = (i >= 6) ? i - 6 : i;
            bool rh = (i >= 6);
            const float *Wt, *bt; int row = 0;
            if (ii == 0){ Wt = rh ? r_Wb : w_Wb; bt = rh ? r_bb : w_bb; }
            else if (ii == 1){ Wt = rh ? r_Wg : w_Wg; bt = rh ? r_bg : w_bg; }
            else if (ii == 2){ Wt = rh ? r_Wp : w_Wp; bt = rh ? r_bp : w_bp; }
            else { Wt = rh ? r_Ws : w_Ws; bt = rh ? r_bs : w_bs; row = ii - 3; }
            Wrow = Wt + (size_t)row * Hsz; bias = bt[row];
          }
          float acc = 0.f;
          if (len == 512){
            int k = ln * 8;
            float4 a0 = *(const float4*)(Wrow + k);
            float4 a1 = *(const float4*)(Wrow + k + 4);
            float4 c0 = *(const float4*)(&s_co[k]);
            float4 c1 = *(const float4*)(&s_co[k + 4]);
            acc = a0.x*c0.x + a0.y*c0.y + a0.z*c0.z + a0.w*c0.w
                + a1.x*c1.x + a1.y*c1.y + a1.z*c1.z + a1.w*c1.w;
          } else {
#pragma unroll 1
            for (int kk = ln; kk < 768; kk += 64){
              float xv = (kk < Hsz) ? s_co[kk] : s_rv[kk - Hsz];
              acc += Wrow[kk] * xv;
            }
          }
          acc = wred64(acc);
          if (ln == 0){
            float v = acc + bias;
            if (mode == 1) v = sigm(v);
            if (mode == 2) out[(size_t)t * Isz + (slot - 1024)] = v;
            else gstore64(&ppub[slot], tg | (unsigned long long)__float_as_uint(v));
          }
        }
      }
    }

    if (t == Tlen - 1) break;   // out(127) done; D..J only produce next-step state

    float betaR = 0.f, invbkR = 0.f;

    // ---- D: poll keyw+scal; write-head content scores (quad-per-row, DPP) ----
    {
      float* Pnx = Pbuf[(t + 1) & 1];
      if (b < NG && tid < 256) gstore(&Pnx[b * 256 + tid], 0.f);
      if (tid < 256) s_a[tid] = pollw(&ppub[tid], TT);
      else if (tid < 268) s_scal[tid - 256] = pollw(&ppub[1280 + (tid - 256)], TT);
      lbar();
      float nk2 = bred512((tid < 256) ? s_a[tid] * s_a[tid] : 0.f);
      float beta  = softplusf(s_scal[0]);
      float invbk = beta / fmaxf(sqrtf(nk2), 1e-12f);
      int row = tid >> 2, q = tid & 3;
      const float* mrow = &s_mem[row * Dsz];
      float d = 0.f;
#pragma unroll
      for (int k = 0; k < 16; ++k){
        int c = (q + 4 * ((k + row) & 15)) * 4;   // rotated chunk: full bank spread
        float4 mv = *(const float4*)(mrow + c);
        float4 kv = *(const float4*)(&s_a[c]);
        d += mv.x*kv.x + mv.y*kv.y + mv.z*kv.z + mv.w*kv.w;
      }
      d = qsum4(d);
      if (q == 0) s_dot[row] = d;
      lbar();
      float e = 0.f;
      if (tid < RPB){
        float score = s_dot[tid] * invbk / fmaxf(s_norm[tid], 1e-12f);
        e = __expf(score - beta);
        s_e[tid] = e;
      }
      float tot = wred64(e);
      if (ln == 0 && wv < 2) s_w2[wv] = tot;
      lbar();
      if (tid == 0){
        float T = s_w2[0] + s_w2[1];
        gstore64(&wEF[b], tg | (unsigned long long)__float_as_uint(s_e[0]));
        gstore64(&wPF[b], tg | (unsigned long long)__float_as_uint(s_ww[0]));
        gstore64(&wEL[b], tg | (unsigned long long)__float_as_uint(s_e[RPB-1]));
        gstore64(&wPL[b], tg | (unsigned long long)__float_as_uint(s_ww[RPB-1]));
        gstore64(&pubD[(size_t)b * PUBSTR], tg | (unsigned long long)__float_as_uint(T));
      }
    }

    // ---- H-pre: poll er/ad/kr; Sw-independent reductions (quad-per-row, DPP) ----
    // mem_new = mv + ww*q, q = ad - mv*er  =>
    //   |mem_new|^2   = A0 + ww*A1 + ww^2*A2
    //   <mem_new,kr>  = B0 + ww*B1
    {
      if (tid < 256) s_a[tid] = pollw(&ppub[256 + tid], TT);          // erase (sigmoided)
      else           s_b[tid - 256] = pollw(&ppub[512 + (tid - 256)], TT);  // add
      if (tid < 256) s_c[tid] = pollw(&ppub[768 + tid], TT);          // keyr
      float nk2r = bred512((tid < 256) ? s_c[tid] * s_c[tid] : 0.f);  // barriers inside
      betaR  = softplusf(s_scal[6]);
      invbkR = betaR / fmaxf(sqrtf(nk2r), 1e-12f);
      int row = tid >> 2, q = tid & 3;
      const float* mrow = &s_mem[row * Dsz];
      float mq = 0.f, qq = 0.f, qk = 0.f, mk = 0.f;
#pragma unroll
      for (int k = 0; k < 16; ++k){
        int c = (q + 4 * ((k + row) & 15)) * 4;
        float4 mv = *(const float4*)(mrow + c);
        float4 er = *(const float4*)(&s_a[c]);
        float4 ad = *(const float4*)(&s_b[c]);
        float4 kr = *(const float4*)(&s_c[c]);
        float qx = ad.x - mv.x * er.x;
        float qy = ad.y - mv.y * er.y;
        float qz = ad.z - mv.z * er.z;
        float qw = ad.w - mv.w * er.w;
        mq += mv.x*qx + mv.y*qy + mv.z*qz + mv.w*qw;
        qq += qx*qx + qy*qy + qz*qz + qw*qw;
        qk += qx*kr.x + qy*kr.y + qz*kr.z + qw*kr.w;
        mk += mv.x*kr.x + mv.y*kr.y + mv.z*kr.z + mv.w*kr.w;
      }
      mq = qsum4(mq); qq = qsum4(qq); qk = qsum4(qk); mk = qsum4(mk);
      if (q == 0){ s_A1[row] = 2.f*mq; s_A2[row] = qq; s_B1[row] = qk; s_B0[row] = mk; }
    }

    // ---- F: write-head shift+sharpen (S_w should already be there) ----
    {
      if (wv == 0 && ln < 4){
        const unsigned long long* bp = (ln == 0) ? &wEF[(b + 1) & (NBLK-1)]
                               : (ln == 1) ? &wPF[(b + 1) & (NBLK-1)]
                               : (ln == 2) ? &wEL[(b - 1) & (NBLK-1)]
                                           : &wPL[(b - 1) & (NBLK-1)];
        s_bd[ln] = pollw(bp, TT);
      }
      float S_w = pubWaitSum(pubD, TT);
      shiftSharpen(0, s_ww, S_w, pubF, TT);
    }

    // ---- H-post: wait Sw; cheap elementwise mem update + per-row fixups ----
    {
      float Sw = pubWaitSum(pubF, TT);
      float invSw = 1.f / (Sw + 1e-8f);
      float4 er4 = *(const float4*)(&s_a[ln * 4]);
      float4 ad4 = *(const float4*)(&s_b[ln * 4]);
#pragma unroll 1
      for (int it = 0; it < 16; ++it){
        int ml = it * 8 + wv;
        int off = ml * Dsz + ln * 4;
        float wwm = s_bw[ml] * invSw;
        float4 mv = *(const float4*)(&s_mem[off]);
        float4 nv;
        nv.x = fmaf(wwm, ad4.x - mv.x * er4.x, mv.x);
        nv.y = fmaf(wwm, ad4.y - mv.y * er4.y, mv.y);
        nv.z = fmaf(wwm, ad4.z - mv.z * er4.z, mv.z);
        nv.w = fmaf(wwm, ad4.w - mv.w * er4.w, mv.w);
        *(float4*)(&s_mem[off]) = nv;
      }
      float e = 0.f;
      if (tid < RPB){
        float wwm = s_bw[tid] * invSw;
        s_ww[tid] = wwm;
        float A0 = s_norm[tid] * s_norm[tid];
        float n2 = fmaf(wwm, fmaf(wwm, s_A2[tid], s_A1[tid]), A0);
        float dt = fmaf(wwm, s_B1[tid], s_B0[tid]);
        float nr = sqrtf(fmaxf(n2, 0.f));
        s_norm[tid] = nr;
        float score = dt * invbkR / fmaxf(nr, 1e-12f);
        e = __expf(score - betaR);
        s_e[tid] = e;
      }
      float tot = wred64(e);
      if (ln == 0 && wv < 2) s_w2[wv] = tot;
      lbar();
      if (tid == 0){
        float T2 = s_w2[0] + s_w2[1];
        gstore64(&rEF[b], tg | (unsigned long long)__float_as_uint(s_e[0]));
        gstore64(&rPF[b], tg | (unsigned long long)__float_as_uint(s_rw[0]));
        gstore64(&rEL[b], tg | (unsigned long long)__float_as_uint(s_e[RPB-1]));
        gstore64(&rPL[b], tg | (unsigned long long)__float_as_uint(s_rw[RPB-1]));
        gstore64(&pubH[(size_t)b * PUBSTR], tg | (unsigned long long)__float_as_uint(T2));
      }
    }

    // ---- J: read sharpen; rvec partials; next-step GEMV hides pubJ wait ----
    {
      if (wv == 0 && ln < 4){
        const unsigned long long* bp = (ln == 0) ? &rEF[(b + 1) & (NBLK-1)]
                               : (ln == 1) ? &rPF[(b + 1) & (NBLK-1)]
                               : (ln == 2) ? &rEL[(b - 1) & (NBLK-1)]
                                           : &rPL[(b - 1) & (NBLK-1)];
        s_bd[ln] = pollw(bp, TT);
      }
      float S_r = pubWaitSum(pubH, TT);
      shiftSharpen(6, s_rw, S_r, nullptr, 0);   // partial left in s_pub
      lbar();
      int col = tid & 255, half = tid >> 8;
      float acc = 0.f;
#pragma unroll 1
      for (int j = half * 64; j < half * 64 + 64; ++j) acc += s_bw[j] * s_mem[j * Dsz + col];
      if (half == 0) s_a[col] = acc;
      lbar();
      if (half == 1) atomicAdd(&Pcur[(b & (NG-1)) * 256 + col], acc + s_a[col]);
      __syncthreads();                           // drain atomics (and D's zeroes)
      if (tid == 0)
        gstore64(&pubJ[(size_t)b * PUBSTR], tg | (unsigned long long)__float_as_uint(s_pub));
      // hide the pubJ wait under next step's x/h GEMV parts
      if (tid < 256) s_a[tid] = inputs[(size_t)(t + 1) * Isz + tid];
      lbar();
      accxh = gemvXH();
      Srcarry = pubWaitSum(pubJ, TT);
    }
  }
}

extern "C" void kernel_launch(void* const* d_in, const int* in_sizes, int n_in,
                              void* d_out, int out_size, void* d_ws, size_t ws_size,
                              hipStream_t stream)
{
  (void)in_sizes; (void)out_size;
  if (n_in < 34) return;
  if (ws_size < (size_t)98304) return;   // ~92KB scratch needed
  Params P;
  for (int i = 0; i < 34; ++i) P.in[i] = (const float*)d_in[i];
  P.out = (float*)d_out;
  P.ws  = (float*)d_ws;
  hipLaunchKernelGGL(ntm_kernel, dim3(NBLK), dim3(NTHR), 0, stream, P);
}

// Round 3
// 3630.608 us; speedup vs baseline: 1.4002x; 1.0093x over previous
//
#include <hip/hip_runtime.h>
#include <math.h>

// Persistent-kernel NTM, R14: single-word fixed-point atomic reduces.
// The 4 global sum-barriers (S_w, Sw, S_r, Sr2) become one u64 atomicAdd per
// block into a per-step slot: count in bits 48+, sum in bits 0..47 (x2^30
// fixed point; all summands in [0,1], totals <= 16384 -> exact, deterministic).
// One lane polls one line (vs 64 lanes x 128 lines). H-post reordered:
// S_r fixups+publish BEFORE mem update (update hides S_r propagation).
// Wo 768-dot vectorized (3x float4). Rest identical to R13.

#define NBLK 128
#define NTHR 512
#define Msz  16384
#define Dsz  256
#define Hsz  512
#define Isz  256
#define Tlen 128
#define RPB  128
#define NG   16

#define FXS  1073741824.0f          // 2^30
#define FXSI (1.0 / 1073741824.0)
#define CNT1 (1ull << 48)

struct Params { const float* in[34]; float* out; float* ws; };

__device__ __forceinline__ float wred64(float v){
#pragma unroll
  for (int o = 32; o > 0; o >>= 1) v += __shfl_xor(v, o, 64);
  return v;
}
__device__ __forceinline__ float wred32(float v){
#pragma unroll
  for (int o = 16; o > 0; o >>= 1) v += __shfl_xor(v, o, 32);
  return v;
}
// sum over each 4-lane quad via DPP quad_perm (no DS ops, no bank conflicts)
__device__ __forceinline__ float qsum4(float v){
  v += __uint_as_float(__builtin_amdgcn_mov_dpp(__float_as_uint(v), 0xB1, 0xF, 0xF, true)); // xor1
  v += __uint_as_float(__builtin_amdgcn_mov_dpp(__float_as_uint(v), 0x4E, 0xF, 0xF, true)); // xor2
  return v;
}
__device__ __forceinline__ float sigm(float x){ return 1.f / (1.f + __expf(-x)); }
__device__ __forceinline__ float softplusf(float x){ return (x > 20.f) ? x : log1pf(__expf(x)); }

__device__ __forceinline__ void gstore(float* p, float v){
  __hip_atomic_store(p, v, __ATOMIC_RELAXED, __HIP_MEMORY_SCOPE_AGENT);
}
__device__ __forceinline__ float gload(const float* p){
  return __hip_atomic_load(p, __ATOMIC_RELAXED, __HIP_MEMORY_SCOPE_AGENT);
}
__device__ __forceinline__ void gstore64(unsigned long long* p, unsigned long long v){
  __hip_atomic_store(p, v, __ATOMIC_RELAXED, __HIP_MEMORY_SCOPE_AGENT);
}
__device__ __forceinline__ unsigned long long gload64(const unsigned long long* p){
  return __hip_atomic_load(p, __ATOMIC_RELAXED, __HIP_MEMORY_SCOPE_AGENT);
}
// lgkmcnt(0)-only barrier: vmcnt=63, expcnt=7, lgkmcnt=0 -> imm 0xC07F
__device__ __forceinline__ void lbar(){
  __builtin_amdgcn_s_waitcnt(0xC07F);
  __builtin_amdgcn_s_barrier();
}
// poll a tagged word until tag >= want; return payload float
__device__ __forceinline__ float pollw(const unsigned long long* p, unsigned want){
  unsigned long long k;
  do { k = gload64(p); } while ((int)((unsigned)(k >> 32) - want) < 0);
  return __uint_as_float((unsigned)k);
}
// fixed-point publish word: count 1 in bits 48+, value*2^30 in low bits
__device__ __forceinline__ unsigned long long fxpack(float v){
  return CNT1 + (unsigned long long)(v * FXS);
}

__global__ void __launch_bounds__(NTHR, 1)
ntm_kernel(Params P)
{
  const int b   = blockIdx.x;
  const int tid = threadIdx.x;
  const int wv  = tid >> 6;   // wave 0..7
  const int ln  = tid & 63;

  // ------- inputs (setup_inputs dict order) -------
  const float* inputs  = P.in[0];
  const float* mem0    = P.in[1];
  const float* read_w0 = P.in[2];
  const float* write_w0= P.in[3];
  const float* W_ih = P.in[4];
  const float* W_hh = P.in[5];
  const float* b_ih = P.in[6];
  const float* b_hh = P.in[7];
  const float* Wo   = P.in[8];
  const float* bo   = P.in[9];
  const float* r_Wk = P.in[10]; const float* r_bk = P.in[11];
  const float* r_Wb = P.in[12]; const float* r_bb = P.in[13];
  const float* r_Wg = P.in[14]; const float* r_bg = P.in[15];
  const float* r_Ws = P.in[16]; const float* r_bs = P.in[17];
  const float* r_Wp = P.in[18]; const float* r_bp = P.in[19];
  const float* w_Wk = P.in[20]; const float* w_bk = P.in[21];
  const float* w_Wb = P.in[22]; const float* w_bb = P.in[23];
  const float* w_Wg = P.in[24]; const float* w_bg = P.in[25];
  const float* w_Ws = P.in[26]; const float* w_bs = P.in[27];
  const float* w_Wp = P.in[28]; const float* w_bp = P.in[29];
  const float* w_We = P.in[30]; const float* w_be = P.in[31];
  const float* w_Wa = P.in[32]; const float* w_ba = P.in[33];
  float* out = P.out;

  // ------- global scratch layout (ws zeroed by harness reset) -------
  float* ws = P.ws;
  float* PA = ws;
  float* PB = ws + 4096;
  unsigned long long* U    = (unsigned long long*)(ws + 8192);
  unsigned long long* hpub = U;                 // 1024
  unsigned long long* ppub = U + 1024;          // 1296
  unsigned long long* wEF  = U + 2320;          // 128 each, contiguous
  unsigned long long* wPF  = wEF + 128;
  unsigned long long* wEL  = wPF + 128;
  unsigned long long* wPL  = wEL + 128;
  unsigned long long* rEF  = wPL + 128;
  unsigned long long* rPF  = rEF + 128;
  unsigned long long* rEL  = rPF + 128;
  unsigned long long* rPL  = rEL + 128;
  unsigned long long* redD = rPL + 128;         // 128 per-step slots
  unsigned long long* redF = redD + Tlen;
  unsigned long long* redH = redF + Tlen;
  unsigned long long* redJ = redH + Tlen;
  unsigned long long* redI = redJ + Tlen;       // 2 init slots
  float* Pbuf[2] = { PA, PB };

  // ------- LDS -------
  __shared__ float s_mem[RPB * Dsz];   // 128KB
  __shared__ float s_co[Hsz];
  __shared__ float s_a[256], s_b[256], s_c[256];
  __shared__ float s_rv[256];
  __shared__ float s_norm[RPB];
  __shared__ float s_e[RPB];
  __shared__ float s_bw[RPB];
  __shared__ float s_rw[RPB];
  __shared__ float s_ww[RPB];
  __shared__ float s_A1[RPB], s_A2[RPB], s_B1[RPB], s_B0[RPB];
  __shared__ float s_dot[RPB];
  __shared__ float s_red[8];
  __shared__ float s_lg[16];
  __shared__ float s_scal[16];
  __shared__ float s_w2[2];
  __shared__ float s_cst[4];
  __shared__ float s_bd[4];
  __shared__ float s_pub;
  __shared__ float s_gval;

  // single-line fixed-point reduce wait: one lane polls, all get the sum
  auto redWait = [&](unsigned long long* slot)->float{
    if (tid == 0){
      unsigned long long k;
      do { k = gload64(slot); } while ((unsigned)(k >> 48) < (unsigned)NBLK);
      s_gval = (float)((double)(k & 0xFFFFFFFFFFFFull) * FXSI);
    }
    lbar();
    return s_gval;
  };

  auto bred512 = [&](float v)->float{
    v = wred64(v);
    lbar();
    if (ln == 0) s_red[wv] = v;
    lbar();
    return s_red[0] + s_red[1] + s_red[2] + s_red[3]
         + s_red[4] + s_red[5] + s_red[6] + s_red[7];
  };

  // shift + sharpen; boundaries from s_bd; partial -> s_pub (+ fx-publish if slot)
  auto shiftSharpen = [&](int si, float* s_prevw, float S, unsigned long long* slot){
    float g     = sigm(s_scal[si + 1]);
    float gamma = softplusf(s_scal[si + 2]) + 1.f;
    float a0 = s_scal[si + 3], a1 = s_scal[si + 4], a2 = s_scal[si + 5];
    float mx = fmaxf(a0, fmaxf(a1, a2));
    float e0 = __expf(a0 - mx), e1 = __expf(a1 - mx), e2 = __expf(a2 - mx);
    float idn = 1.f / (e0 + e1 + e2);
    float s0 = e0 * idn, s1 = e1 * idn, s2 = e2 * idn;
    float invS = 1.f / S;
    float w = 0.f;
    if (tid < RPB){
      float gc = g * invS, gp = 1.f - g;
      float em = s_e[tid],  pm = s_prevw[tid];
      float e1n = (tid < RPB-1) ? s_e[tid+1]     : s_bd[0];
      float p1n = (tid < RPB-1) ? s_prevw[tid+1] : s_bd[1];
      float e2n = (tid > 0)     ? s_e[tid-1]     : s_bd[2];
      float p2n = (tid > 0)     ? s_prevw[tid-1] : s_bd[3];
      float gwm = gc * em  + gp * pm;
      float gw1 = gc * e1n + gp * p1n;   // roll(gw,-1)
      float gw2 = gc * e2n + gp * p2n;   // roll(gw,+1)
      float sh = s0 * gw1 + s1 * gwm + s2 * gw2;
      w = powf(sh, gamma);
      s_bw[tid] = w;
    }
    float tot = wred64(w);
    if (ln == 0 && wv < 2) s_w2[wv] = tot;
    lbar();
    if (tid == 0){
      float T2 = s_w2[0] + s_w2[1];
      s_pub = T2;
      if (slot) atomicAdd(slot, fxpack(T2));
    }
  };

  // LSTM GEMV, x-part (s_a) + h-part (s_co); rvec part added later in A
  auto gemvXH = [&]()->float{
    int dd = tid >> 5, l = tid & 31;
    int r = (dd >> 2) * Hsz + (b << 2) + (dd & 3);
    const float* wi = W_ih + (size_t)r * (Isz + Dsz);
    const float* wh = W_hh + (size_t)r * Hsz;
    float acc = 0.f;
#pragma unroll
    for (int it = 0; it < 2; ++it){
      int k = it * 128 + l * 4;
      float4 a = *(const float4*)(wi + k);
      float4 x = *(const float4*)(&s_a[k]);
      acc += a.x*x.x + a.y*x.y + a.z*x.z + a.w*x.w;
    }
#pragma unroll
    for (int it = 0; it < 4; ++it){
      int k = it * 128 + l * 4;
      float4 hw = *(const float4*)(wh + k);
      float4 hv = *(const float4*)(&s_co[k]);
      acc += hw.x*hv.x + hw.y*hv.y + hw.z*hv.z + hw.w*hv.w;
    }
    return acc;
  };

  float Srcarry = 1.f;
  float accxh   = 0.f;

  // ------- INIT1: zero parts; load initial weights/state (redI[0]) -------
  {
    if (b < NG && tid < 256){ gstore(&PA[b*256 + tid], 0.f); gstore(&PB[b*256 + tid], 0.f); }
    if (tid < RPB){
      s_rw[tid] = read_w0[b * RPB + tid];
      s_ww[tid] = write_w0[b * RPB + tid];
    }
    if (tid < 4) s_cst[tid] = 0.f;
    s_co[tid] = 0.f;
    __syncthreads();                               // drain zero stores
    if (tid == 0) atomicAdd(redI + 0, CNT1);
    redWait(redI + 0);
  }

  // ------- INIT2: memory -> LDS, norms, initial rvec partials (redI[1]) -------
  {
#pragma unroll 1
    for (int it = 0; it < 16; ++it){
      int ml = it * 8 + wv;
      int m  = b * RPB + ml;
      float4 v = *(const float4*)(mem0 + (size_t)m * Dsz + ln * 4);
      *(float4*)(&s_mem[ml * Dsz + ln * 4]) = v;
      float n2 = wred64(v.x*v.x + v.y*v.y + v.z*v.z + v.w*v.w);
      if (ln == 0) s_norm[ml] = sqrtf(n2);
    }
    lbar();
    int col = tid & 255, half = tid >> 8;
    float acc = 0.f;
#pragma unroll 1
    for (int j = half * 64; j < half * 64 + 64; ++j) acc += s_rw[j] * s_mem[j * Dsz + col];
    if (half == 0) s_a[col] = acc;
    lbar();
    if (half == 1) atomicAdd(&PB[(b & (NG-1)) * 256 + col], acc + s_a[col]);
    __syncthreads();                               // drain atomics
    if (tid < 256) s_a[tid] = inputs[tid];         // stage x(0)
    if (tid == 0) atomicAdd(redI + 1, CNT1);
    lbar();
    accxh = gemvXH();                              // h = 0 -> W_hh part is 0
    redWait(redI + 1);
  }

  // =================== time loop ===================
  for (int t = 0; t < Tlen; ++t){
    const unsigned TT = (unsigned)(t + 3);
    const unsigned long long tg = (unsigned long long)TT << 32;
    float* Pcur = Pbuf[t & 1];          // J(t) atomics
    float* Prd  = Pbuf[(t + 1) & 1];    // A(t) reads

    // ---- A: deferred rw/rvec normalize; finish LSTM; publish tagged h ----
    {
      float SrDiv = (t == 0) ? 1.f : (Srcarry + 1e-8f);
      if (t > 0 && tid < RPB) s_rw[tid] = s_bw[tid] / SrDiv;
      if (tid < 256){
        float rvv = 0.f;
#pragma unroll
        for (int p = 0; p < NG; ++p) rvv += gload(&Prd[p * 256 + tid]);
        s_rv[tid] = rvv / SrDiv;
      }
      lbar();
      int dd = tid >> 5, l = tid & 31;
      int r = (dd >> 2) * Hsz + (b << 2) + (dd & 3);
      const float* wi = W_ih + (size_t)r * (Isz + Dsz) + Isz;
      float acc = accxh;
#pragma unroll
      for (int it = 0; it < 2; ++it){
        int k = it * 128 + l * 4;
        float4 a = *(const float4*)(wi + k);
        float4 x = *(const float4*)(&s_rv[k]);
        acc += a.x*x.x + a.y*x.y + a.z*x.z + a.w*x.w;
      }
      acc = wred32(acc);
      if (l == 0) s_lg[dd] = acc + b_ih[r] + b_hh[r];
      lbar();
      if (tid < 4){
        float iv = s_lg[tid], fv = s_lg[4 + tid], gv = s_lg[8 + tid], ov = s_lg[12 + tid];
        float cn = sigm(fv) * s_cst[tid] + sigm(iv) * tanhf(gv);
        s_cst[tid] = cn;
        float hn = sigm(ov) * tanhf(cn);
        gstore64(&hpub[(size_t)b * 8 + tid], tg | (unsigned long long)__float_as_uint(hn));
      }
    }

    // ---- C: poll tagged h; projections -> tagged slot words / out ----
    {
      s_co[tid] = pollw(&hpub[(size_t)(tid >> 2) * 8 + (tid & 3)], TT);
      lbar();
#pragma unroll
      for (int qi = 0; qi < 2; ++qi){
        int q = qi * 8 + wv;          // 0..15
        int slot = q * 128 + b;
        if (slot < 1292){
          const float* Wrow = nullptr; float bias = 0.f; int len = 512;
          int mode = 0;  // 0: tagged pub, 1: sigmoid + pub, 2: out store
          if (slot < 256){ Wrow = w_Wk + (size_t)slot * Hsz; bias = w_bk[slot]; }
          else if (slot < 512){ int i = slot - 256; Wrow = w_We + (size_t)i * Hsz; bias = w_be[i]; mode = 1; }
          else if (slot < 768){ int i = slot - 512; Wrow = w_Wa + (size_t)i * Hsz; bias = w_ba[i]; }
          else if (slot < 1024){ int i = slot - 768; Wrow = r_Wk + (size_t)i * Hsz; bias = r_bk[i]; }
          else if (slot < 1280){ int i = slot - 1024; Wrow = Wo + (size_t)i * (Hsz + Dsz); bias = bo[i]; len = 768; mode = 2; }
          else {
            int i = slot - 1280;
            int ii = (i >= 6) ? i - 6 : i;
            bool rh = (i >= 6);
            const float *Wt, *bt; int row = 0;
            if (ii == 0){ Wt = rh ? r_Wb : w_Wb; bt = rh ? r_bb : w_bb; }
            else if (ii == 1){ Wt = rh ? r_Wg : w_Wg; bt = rh ? r_bg : w_bg; }
            else if (ii == 2){ Wt = rh ? r_Wp : w_Wp; bt = rh ? r_bp : w_bp; }
            else { Wt = rh ? r_Ws : w_Ws; bt = rh ? r_bs : w_bs; row = ii - 3; }
            Wrow = Wt + (size_t)row * Hsz; bias = bt[row];
          }
          float acc = 0.f;
          if (len == 512){
            int k = ln * 8;
            float4 a0 = *(const float4*)(Wrow + k);
            float4 a1 = *(const float4*)(Wrow + k + 4);
            float4 c0 = *(const float4*)(&s_co[k]);
            float4 c1 = *(const float4*)(&s_co[k + 4]);
            acc = a0.x*c0.x + a0.y*c0.y + a0.z*c0.z + a0.w*c0.w
                + a1.x*c1.x + a1.y*c1.y + a1.z*c1.z + a1.w*c1.w;
          } else {
            int k = ln * 4;
            float4 w0 = *(const float4*)(Wrow + k);
            float4 w1 = *(const float4*)(Wrow + 256 + k);
            float4 w2 = *(const float4*)(Wrow + 512 + k);
            float4 c0 = *(const float4*)(&s_co[k]);
            float4 c1 = *(const float4*)(&s_co[256 + k]);
            float4 r0 = *(const float4*)(&s_rv[k]);
            acc = w0.x*c0.x + w0.y*c0.y + w0.z*c0.z + w0.w*c0.w
                + w1.x*c1.x + w1.y*c1.y + w1.z*c1.z + w1.w*c1.w
                + w2.x*r0.x + w2.y*r0.y + w2.z*r0.z + w2.w*r0.w;
          }
          acc = wred64(acc);
          if (ln == 0){
            float v = acc + bias;
            if (mode == 1) v = sigm(v);
            if (mode == 2) out[(size_t)t * Isz + (slot - 1024)] = v;
            else gstore64(&ppub[slot], tg | (unsigned long long)__float_as_uint(v));
          }
        }
      }
    }

    if (t == Tlen - 1) break;   // out(127) done; D..J only produce next-step state

    float betaR = 0.f, invbkR = 0.f;

    // ---- D: poll keyw+scal; write-head content scores (quad-per-row, DPP) ----
    {
      float* Pnx = Pbuf[(t + 1) & 1];
      if (b < NG && tid < 256) gstore(&Pnx[b * 256 + tid], 0.f);
      if (tid < 256) s_a[tid] = pollw(&ppub[tid], TT);
      else if (tid < 268) s_scal[tid - 256] = pollw(&ppub[1280 + (tid - 256)], TT);
      lbar();
      float nk2 = bred512((tid < 256) ? s_a[tid] * s_a[tid] : 0.f);
      float beta  = softplusf(s_scal[0]);
      float invbk = beta / fmaxf(sqrtf(nk2), 1e-12f);
      int row = tid >> 2, q = tid & 3;
      const float* mrow = &s_mem[row * Dsz];
      float d = 0.f;
#pragma unroll
      for (int k = 0; k < 16; ++k){
        int c = (q + 4 * ((k + row) & 15)) * 4;   // rotated chunk: full bank spread
        float4 mv = *(const float4*)(mrow + c);
        float4 kv = *(const float4*)(&s_a[c]);
        d += mv.x*kv.x + mv.y*kv.y + mv.z*kv.z + mv.w*kv.w;
      }
      d = qsum4(d);
      if (q == 0) s_dot[row] = d;
      lbar();
      float e = 0.f;
      if (tid < RPB){
        float score = s_dot[tid] * invbk / fmaxf(s_norm[tid], 1e-12f);
        e = __expf(score - beta);
        s_e[tid] = e;
      }
      float tot = wred64(e);
      if (ln == 0 && wv < 2) s_w2[wv] = tot;
      lbar();
      if (tid == 0){
        float T = s_w2[0] + s_w2[1];
        gstore64(&wEF[b], tg | (unsigned long long)__float_as_uint(s_e[0]));
        gstore64(&wPF[b], tg | (unsigned long long)__float_as_uint(s_ww[0]));
        gstore64(&wEL[b], tg | (unsigned long long)__float_as_uint(s_e[RPB-1]));
        gstore64(&wPL[b], tg | (unsigned long long)__float_as_uint(s_ww[RPB-1]));
        atomicAdd(redD + t, fxpack(T));
      }
    }

    // ---- H-pre: poll er/ad/kr; Sw-independent reductions (quad-per-row, DPP) ----
    // mem_new = mv + ww*q, q = ad - mv*er  =>
    //   |mem_new|^2   = A0 + ww*A1 + ww^2*A2
    //   <mem_new,kr>  = B0 + ww*B1
    {
      if (tid < 256) s_a[tid] = pollw(&ppub[256 + tid], TT);          // erase (sigmoided)
      else           s_b[tid - 256] = pollw(&ppub[512 + (tid - 256)], TT);  // add
      if (tid < 256) s_c[tid] = pollw(&ppub[768 + tid], TT);          // keyr
      float nk2r = bred512((tid < 256) ? s_c[tid] * s_c[tid] : 0.f);  // barriers inside
      betaR  = softplusf(s_scal[6]);
      invbkR = betaR / fmaxf(sqrtf(nk2r), 1e-12f);
      int row = tid >> 2, q = tid & 3;
      const float* mrow = &s_mem[row * Dsz];
      float mq = 0.f, qq = 0.f, qk = 0.f, mk = 0.f;
#pragma unroll
      for (int k = 0; k < 16; ++k){
        int c = (q + 4 * ((k + row) & 15)) * 4;
        float4 mv = *(const float4*)(mrow + c);
        float4 er = *(const float4*)(&s_a[c]);
        float4 ad = *(const float4*)(&s_b[c]);
        float4 kr = *(const float4*)(&s_c[c]);
        float qx = ad.x - mv.x * er.x;
        float qy = ad.y - mv.y * er.y;
        float qz = ad.z - mv.z * er.z;
        float qw = ad.w - mv.w * er.w;
        mq += mv.x*qx + mv.y*qy + mv.z*qz + mv.w*qw;
        qq += qx*qx + qy*qy + qz*qz + qw*qw;
        qk += qx*kr.x + qy*kr.y + qz*kr.z + qw*kr.w;
        mk += mv.x*kr.x + mv.y*kr.y + mv.z*kr.z + mv.w*kr.w;
      }
      mq = qsum4(mq); qq = qsum4(qq); qk = qsum4(qk); mk = qsum4(mk);
      if (q == 0){ s_A1[row] = 2.f*mq; s_A2[row] = qq; s_B1[row] = qk; s_B0[row] = mk; }
    }

    // ---- F: write-head shift+sharpen (S_w should already be there) ----
    {
      if (wv == 0 && ln < 4){
        const unsigned long long* bp = (ln == 0) ? &wEF[(b + 1) & (NBLK-1)]
                               : (ln == 1) ? &wPF[(b + 1) & (NBLK-1)]
                               : (ln == 2) ? &wEL[(b - 1) & (NBLK-1)]
                                           : &wPL[(b - 1) & (NBLK-1)];
        s_bd[ln] = pollw(bp, TT);
      }
      float S_w = redWait(redD + t);   // lbar inside publishes s_bd too
      shiftSharpen(0, s_ww, S_w, redF + t);
    }

    // ---- H-post: wait Sw; S_r fixups + publish FIRST, then mem update ----
    {
      float Sw = redWait(redF + t);
      float invSw = 1.f / (Sw + 1e-8f);
      float4 er4 = *(const float4*)(&s_a[ln * 4]);
      float4 ad4 = *(const float4*)(&s_b[ln * 4]);
      float e = 0.f;
      if (tid < RPB){
        float wwm = s_bw[tid] * invSw;
        s_ww[tid] = wwm;
        float A0 = s_norm[tid] * s_norm[tid];
        float n2 = fmaf(wwm, fmaf(wwm, s_A2[tid], s_A1[tid]), A0);
        float dt = fmaf(wwm, s_B1[tid], s_B0[tid]);
        float nr = sqrtf(fmaxf(n2, 0.f));
        s_norm[tid] = nr;
        float score = dt * invbkR / fmaxf(nr, 1e-12f);
        e = __expf(score - betaR);
        s_e[tid] = e;
      }
      float tot = wred64(e);
      if (ln == 0 && wv < 2) s_w2[wv] = tot;
      lbar();
      if (tid == 0){
        float T2 = s_w2[0] + s_w2[1];
        gstore64(&rEF[b], tg | (unsigned long long)__float_as_uint(s_e[0]));
        gstore64(&rPF[b], tg | (unsigned long long)__float_as_uint(s_rw[0]));
        gstore64(&rEL[b], tg | (unsigned long long)__float_as_uint(s_e[RPB-1]));
        gstore64(&rPL[b], tg | (unsigned long long)__float_as_uint(s_rw[RPB-1]));
        atomicAdd(redH + t, fxpack(T2));
      }
      // mem update runs while S_r propagates
#pragma unroll 1
      for (int it = 0; it < 16; ++it){
        int ml = it * 8 + wv;
        int off = ml * Dsz + ln * 4;
        float wwm = s_bw[ml] * invSw;
        float4 mv = *(const float4*)(&s_mem[off]);
        float4 nv;
        nv.x = fmaf(wwm, ad4.x - mv.x * er4.x, mv.x);
        nv.y = fmaf(wwm, ad4.y - mv.y * er4.y, mv.y);
        nv.z = fmaf(wwm, ad4.z - mv.z * er4.z, mv.z);
        nv.w = fmaf(wwm, ad4.w - mv.w * er4.w, mv.w);
        *(float4*)(&s_mem[off]) = nv;
      }
    }

    // ---- J: read sharpen; rvec partials; next-step GEMV hides redJ wait ----
    {
      if (wv == 0 && ln < 4){
        const unsigned long long* bp = (ln == 0) ? &rEF[(b + 1) & (NBLK-1)]
                               : (ln == 1) ? &rPF[(b + 1) & (NBLK-1)]
                               : (ln == 2) ? &rEL[(b - 1) & (NBLK-1)]
                                           : &rPL[(b - 1) & (NBLK-1)];
        s_bd[ln] = pollw(bp, TT);
      }
      float S_r = redWait(redH + t);
      shiftSharpen(6, s_rw, S_r, nullptr);   // partial left in s_pub
      lbar();
      int col = tid & 255, half = tid >> 8;
      float acc = 0.f;
#pragma unroll 1
      for (int j = half * 64; j < half * 64 + 64; ++j) acc += s_bw[j] * s_mem[j * Dsz + col];
      if (half == 0) s_a[col] = acc;
      lbar();
      if (half == 1) atomicAdd(&Pcur[(b & (NG-1)) * 256 + col], acc + s_a[col]);
      __syncthreads();                           // drain atomics (and D's zeroes)
      if (tid == 0) atomicAdd(redJ + t, fxpack(s_pub));
      // hide the redJ wait under next step's x/h GEMV parts
      if (tid < 256) s_a[tid] = inputs[(size_t)(t + 1) * Isz + tid];
      lbar();
      accxh = gemvXH();
      Srcarry = redWait(redJ + t);
    }
  }
}

extern "C" void kernel_launch(void* const* d_in, const int* in_sizes, int n_in,
                              void* d_out, int out_size, void* d_ws, size_t ws_size,
                              hipStream_t stream)
{
  (void)in_sizes; (void)out_size;
  if (n_in < 34) return;
  if (ws_size < (size_t)98304) return;
  Params P;
  for (int i = 0; i < 34; ++i) P.in[i] = (const float*)d_in[i];
  P.out = (float*)d_out;
  P.ws  = (float*)d_ws;
  hipLaunchKernelGGL(ntm_kernel, dim3(NBLK), dim3(NTHR), 0, stream, P);
}

// Round 8
// 3622.250 us; speedup vs baseline: 1.4034x; 1.0023x over previous
//
#include <hip/hip_runtime.h>
#include <math.h>

// Persistent-kernel NTM, R19 = R14 (verified passing, 3542us) + 8-way-spread
// hierarchical fixed-point reduces. R15-R18's projection-atomic topology is
// abandoned (unlocated genuine bug). Change vs R14 is ONLY the reduce plumbing:
// each per-step sum barrier redD/F/H/J becomes 8 slots (slot = b&7, slots 1KiB
// apart -> distinct L2 lines, 16 atomics/slot vs 128/line); the waiter polls
// all 8 lines until total count==128 and sums payloads. Integer adds commute
// -> totals are BIT-IDENTICAL to R14's single-word sums. Dataflow untouched.

#define NBLK 128
#define NTHR 512
#define Msz  16384
#define Dsz  256
#define Hsz  512
#define Isz  256
#define Tlen 128
#define RPB  128
#define NG   16

#define CNT1 (1ull << 48)

struct Params { const float* in[34]; float* out; float* ws; };

__device__ __forceinline__ float wred64(float v){
#pragma unroll
  for (int o = 32; o > 0; o >>= 1) v += __shfl_xor(v, o, 64);
  return v;
}
__device__ __forceinline__ float wred32(float v){
#pragma unroll
  for (int o = 16; o > 0; o >>= 1) v += __shfl_xor(v, o, 32);
  return v;
}
// sum over each 4-lane quad via DPP quad_perm (no DS ops, no bank conflicts)
__device__ __forceinline__ float qsum4(float v){
  v += __uint_as_float(__builtin_amdgcn_mov_dpp(__float_as_uint(v), 0xB1, 0xF, 0xF, true)); // xor1
  v += __uint_as_float(__builtin_amdgcn_mov_dpp(__float_as_uint(v), 0x4E, 0xF, 0xF, true)); // xor2
  return v;
}
__device__ __forceinline__ float sigm(float x){ return 1.f / (1.f + __expf(-x)); }
__device__ __forceinline__ float softplusf(float x){ return (x > 20.f) ? x : log1pf(__expf(x)); }

__device__ __forceinline__ void gstore(float* p, float v){
  __hip_atomic_store(p, v, __ATOMIC_RELAXED, __HIP_MEMORY_SCOPE_AGENT);
}
__device__ __forceinline__ float gload(const float* p){
  return __hip_atomic_load(p, __ATOMIC_RELAXED, __HIP_MEMORY_SCOPE_AGENT);
}
__device__ __forceinline__ void gstore64(unsigned long long* p, unsigned long long v){
  __hip_atomic_store(p, v, __ATOMIC_RELAXED, __HIP_MEMORY_SCOPE_AGENT);
}
__device__ __forceinline__ unsigned long long gload64(const unsigned long long* p){
  return __hip_atomic_load(p, __ATOMIC_RELAXED, __HIP_MEMORY_SCOPE_AGENT);
}
// lgkmcnt(0)-only barrier: vmcnt=63, expcnt=7, lgkmcnt=0 -> imm 0xC07F
__device__ __forceinline__ void lbar(){
  __builtin_amdgcn_s_waitcnt(0xC07F);
  __builtin_amdgcn_s_barrier();
}
// poll a tagged word until tag >= want; return payload float
__device__ __forceinline__ float pollw(const unsigned long long* p, unsigned want){
  unsigned long long k;
  do { k = gload64(p); } while ((int)((unsigned)(k >> 32) - want) < 0);
  return __uint_as_float((unsigned)k);
}
// fixed-point publish word: count 1 in bits 48+, value*2^32 in low 48 bits
__device__ __forceinline__ unsigned long long fxpack(float v){
  return CNT1 + (unsigned long long)((double)v * 4294967296.0);
}

__global__ void __launch_bounds__(NTHR, 1)
ntm_kernel(Params P)
{
  const int b   = blockIdx.x;
  const int tid = threadIdx.x;
  const int wv  = tid >> 6;   // wave 0..7
  const int ln  = tid & 63;

  // ------- inputs (setup_inputs dict order) -------
  const float* inputs  = P.in[0];
  const float* mem0    = P.in[1];
  const float* read_w0 = P.in[2];
  const float* write_w0= P.in[3];
  const float* W_ih = P.in[4];
  const float* W_hh = P.in[5];
  const float* b_ih = P.in[6];
  const float* b_hh = P.in[7];
  const float* Wo   = P.in[8];
  const float* bo   = P.in[9];
  const float* r_Wk = P.in[10]; const float* r_bk = P.in[11];
  const float* r_Wb = P.in[12]; const float* r_bb = P.in[13];
  const float* r_Wg = P.in[14]; const float* r_bg = P.in[15];
  const float* r_Ws = P.in[16]; const float* r_bs = P.in[17];
  const float* r_Wp = P.in[18]; const float* r_bp = P.in[19];
  const float* w_Wk = P.in[20]; const float* w_bk = P.in[21];
  const float* w_Wb = P.in[22]; const float* w_bb = P.in[23];
  const float* w_Wg = P.in[24]; const float* w_bg = P.in[25];
  const float* w_Ws = P.in[26]; const float* w_bs = P.in[27];
  const float* w_Wp = P.in[28]; const float* w_bp = P.in[29];
  const float* w_We = P.in[30]; const float* w_be = P.in[31];
  const float* w_Wa = P.in[32]; const float* w_ba = P.in[33];
  float* out = P.out;

  // ------- global scratch layout (ws zeroed at reset) -------
  float* ws = P.ws;
  float* PA = ws;                    // 4096 (rvec partials, 16 groups)
  float* PB = ws + 4096;             // 4096
  unsigned long long* U = (unsigned long long*)(ws + 8192);
  unsigned long long* hpub = U;          // 1024 (128 blocks x 8, tagged h words)
  unsigned long long* ppub = U + 1024;   // 1296 tagged projection slots
  unsigned long long* wEF  = U + 2320;   // boundary words, 128 each
  unsigned long long* wPF  = wEF + 128;
  unsigned long long* wEL  = wPF + 128;
  unsigned long long* wPL  = wEL + 128;
  unsigned long long* rEF  = wPL + 128;
  unsigned long long* rPF  = rEF + 128;
  unsigned long long* rEL  = rPF + 128;
  unsigned long long* rPL  = rEL + 128;
  // 8-way spread reduce slots: redX[slot][t], slot stride = Tlen (1KiB lines)
  unsigned long long* redD = U + 3344;          // 8*Tlen = 1024
  unsigned long long* redF = redD + 8 * Tlen;
  unsigned long long* redH = redF + 8 * Tlen;
  unsigned long long* redJ = redH + 8 * Tlen;
  unsigned long long* redI = redJ + 8 * Tlen;   // 2 init slots (single-word)
  float* Pbuf[2] = { PA, PB };
  const int slot = b & 7;

  // ------- LDS -------
  __shared__ float s_mem[RPB * Dsz];   // 128KB
  __shared__ float s_co[Hsz];
  __shared__ float s_a[256];
  __shared__ float s_er[256], s_ad[256], s_kr[256];
  __shared__ float s_rv[256];
  __shared__ float s_norm[RPB];
  __shared__ float s_e[RPB];
  __shared__ float s_bw[RPB];
  __shared__ float s_rw[RPB];
  __shared__ float s_ww[RPB];
  __shared__ float s_A1[RPB], s_A2[RPB], s_B1[RPB], s_B0[RPB];
  __shared__ float s_dot[RPB];
  __shared__ float s_red[8];
  __shared__ float s_lg[16];
  __shared__ float s_scal[16];
  __shared__ float s_w2[2];
  __shared__ float s_cst[4];
  __shared__ float s_bd[4];
  __shared__ float s_pub;
  __shared__ float s_gval;

  // 8-slot reduce wait: tid0 polls 8 spread lines until total count==128,
  // sums fixed-point payloads (integer adds -> bit-identical to 1-word sum).
  auto redWait8 = [&](unsigned long long* base, int t)->float{
    if (tid == 0){
      unsigned long long k0,k1,k2,k3,k4,k5,k6,k7;
      for (;;){
        k0 = gload64(base + 0*Tlen + t); k1 = gload64(base + 1*Tlen + t);
        k2 = gload64(base + 2*Tlen + t); k3 = gload64(base + 3*Tlen + t);
        k4 = gload64(base + 4*Tlen + t); k5 = gload64(base + 5*Tlen + t);
        k6 = gload64(base + 6*Tlen + t); k7 = gload64(base + 7*Tlen + t);
        unsigned c = (unsigned)(k0>>48) + (unsigned)(k1>>48)
                   + (unsigned)(k2>>48) + (unsigned)(k3>>48)
                   + (unsigned)(k4>>48) + (unsigned)(k5>>48)
                   + (unsigned)(k6>>48) + (unsigned)(k7>>48);
        if (c >= (unsigned)NBLK) break;
      }
      const unsigned long long m = 0xFFFFFFFFFFFFull;
      unsigned long long s = (k0&m)+(k1&m)+(k2&m)+(k3&m)+(k4&m)+(k5&m)+(k6&m)+(k7&m);
      s_gval = (float)((double)s * (1.0 / 4294967296.0));
    }
    lbar();
    return s_gval;
  };
  // single-word wait (init only)
  auto redWait1 = [&](unsigned long long* p)->float{
    if (tid == 0){
      unsigned long long k;
      do { k = gload64(p); } while ((unsigned)(k >> 48) < (unsigned)NBLK);
      s_gval = (float)((double)(k & 0xFFFFFFFFFFFFull) * (1.0 / 4294967296.0));
    }
    lbar();
    return s_gval;
  };

  auto bred512 = [&](float v)->float{
    v = wred64(v);
    lbar();
    if (ln == 0) s_red[wv] = v;
    lbar();
    return s_red[0] + s_red[1] + s_red[2] + s_red[3]
         + s_red[4] + s_red[5] + s_red[6] + s_red[7];
  };

  // shift + sharpen; boundaries from s_bd; partial -> s_pub (+ fx-publish if slotp)
  auto shiftSharpen = [&](int si, float* s_prevw, float S, unsigned long long* slotp){
    float g     = sigm(s_scal[si + 1]);
    float gamma = softplusf(s_scal[si + 2]) + 1.f;
    float a0 = s_scal[si + 3], a1 = s_scal[si + 4], a2 = s_scal[si + 5];
    float mx = fmaxf(a0, fmaxf(a1, a2));
    float e0 = __expf(a0 - mx), e1 = __expf(a1 - mx), e2 = __expf(a2 - mx);
    float idn = 1.f / (e0 + e1 + e2);
    float s0 = e0 * idn, s1 = e1 * idn, s2 = e2 * idn;
    float invS = 1.f / S;
    float w = 0.f;
    if (tid < RPB){
      float gc = g * invS, gp = 1.f - g;
      float em = s_e[tid],  pm = s_prevw[tid];
      float e1n = (tid < RPB-1) ? s_e[tid+1]     : s_bd[0];
      float p1n = (tid < RPB-1) ? s_prevw[tid+1] : s_bd[1];
      float e2n = (tid > 0)     ? s_e[tid-1]     : s_bd[2];
      float p2n = (tid > 0)     ? s_prevw[tid-1] : s_bd[3];
      float gwm = gc * em  + gp * pm;
      float gw1 = gc * e1n + gp * p1n;   // roll(gw,-1)
      float gw2 = gc * e2n + gp * p2n;   // roll(gw,+1)
      float sh = s0 * gw1 + s1 * gwm + s2 * gw2;
      w = powf(sh, gamma);
      s_bw[tid] = w;
    }
    float tot = wred64(w);
    if (ln == 0 && wv < 2) s_w2[wv] = tot;
    lbar();
    if (tid == 0){
      float T2 = s_w2[0] + s_w2[1];
      s_pub = T2;
      if (slotp) atomicAdd(slotp, fxpack(T2));
    }
  };

  // LSTM GEMV, x-part (s_a) + h-part (s_co); rvec part added later in A
  auto gemvXH = [&]()->float{
    int dd = tid >> 5, l = tid & 31;
    int r = (dd >> 2) * Hsz + (b << 2) + (dd & 3);
    const float* wi = W_ih + (size_t)r * (Isz + Dsz);
    const float* wh = W_hh + (size_t)r * Hsz;
    float acc = 0.f;
#pragma unroll
    for (int it = 0; it < 2; ++it){
      int k = it * 128 + l * 4;
      float4 a = *(const float4*)(wi + k);
      float4 x = *(const float4*)(&s_a[k]);
      acc += a.x*x.x + a.y*x.y + a.z*x.z + a.w*x.w;
    }
#pragma unroll
    for (int it = 0; it < 4; ++it){
      int k = it * 128 + l * 4;
      float4 hw = *(const float4*)(wh + k);
      float4 hv = *(const float4*)(&s_co[k]);
      acc += hw.x*hv.x + hw.y*hv.y + hw.z*hv.z + hw.w*hv.w;
    }
    return acc;
  };

  float Srcarry = 1.f;
  float accxh   = 0.f;

  // ------- INIT1: zero parts; load initial state -------
  {
    if (b < NG && tid < 256){ gstore(&PA[b*256 + tid], 0.f); gstore(&PB[b*256 + tid], 0.f); }
    if (tid < RPB){
      s_rw[tid] = read_w0[b * RPB + tid];
      s_ww[tid] = write_w0[b * RPB + tid];
    }
    if (tid < 4) s_cst[tid] = 0.f;
    s_co[tid] = 0.f;
    __syncthreads();                               // drain zero stores
    if (tid == 0) atomicAdd(redI + 0, CNT1);
    redWait1(redI + 0);
  }

  // ------- INIT2: memory -> LDS, norms, initial rvec partials -------
  {
#pragma unroll 1
    for (int it = 0; it < 16; ++it){
      int ml = it * 8 + wv;
      int m  = b * RPB + ml;
      float4 v = *(const float4*)(mem0 + (size_t)m * Dsz + ln * 4);
      *(float4*)(&s_mem[ml * Dsz + ln * 4]) = v;
      float n2 = wred64(v.x*v.x + v.y*v.y + v.z*v.z + v.w*v.w);
      if (ln == 0) s_norm[ml] = sqrtf(n2);
    }
    lbar();
    int col = tid & 255, half = tid >> 8;
    float acc = 0.f;
#pragma unroll 1
    for (int j = half * 64; j < half * 64 + 64; ++j) acc += s_rw[j] * s_mem[j * Dsz + col];
    if (half == 0) s_a[col] = acc;
    lbar();
    if (half == 1) atomicAdd(&PB[(b & (NG-1)) * 256 + col], acc + s_a[col]);
    __syncthreads();                               // drain atomics
    if (tid < 256) s_a[tid] = inputs[tid];         // stage x(0)
    if (tid == 0) atomicAdd(redI + 1, CNT1);
    lbar();
    accxh = gemvXH();                              // h = 0 -> W_hh part is 0
    redWait1(redI + 1);
  }

  // =================== time loop ===================
  for (int t = 0; t < Tlen; ++t){
    const unsigned TT = (unsigned)(t + 3);
    const unsigned long long tg = (unsigned long long)TT << 32;
    float* Pcur = Pbuf[t & 1];          // J(t) atomics
    float* Prd  = Pbuf[(t + 1) & 1];    // A(t) reads

    // ---- A: deferred rw/rvec normalize; finish LSTM; publish tagged h ----
    {
      float SrDiv = (t == 0) ? 1.f : (Srcarry + 1e-8f);
      if (t > 0 && tid < RPB) s_rw[tid] = s_bw[tid] / SrDiv;
      if (tid < 256){
        float rvv = 0.f;
#pragma unroll
        for (int p = 0; p < NG; ++p) rvv += gload(&Prd[p * 256 + tid]);
        s_rv[tid] = rvv / SrDiv;
      }
      lbar();
      int dd = tid >> 5, l = tid & 31;
      int r = (dd >> 2) * Hsz + (b << 2) + (dd & 3);
      const float* wi = W_ih + (size_t)r * (Isz + Dsz) + Isz;
      float acc = accxh;
#pragma unroll
      for (int it = 0; it < 2; ++it){
        int k = it * 128 + l * 4;
        float4 a = *(const float4*)(wi + k);
        float4 x = *(const float4*)(&s_rv[k]);
        acc += a.x*x.x + a.y*x.y + a.z*x.z + a.w*x.w;
      }
      acc = wred32(acc);
      if (l == 0) s_lg[dd] = acc + b_ih[r] + b_hh[r];
      lbar();
      if (tid < 4){
        float iv = s_lg[tid], fv = s_lg[4 + tid], gv = s_lg[8 + tid], ov = s_lg[12 + tid];
        float cn = sigm(fv) * s_cst[tid] + sigm(iv) * tanhf(gv);
        s_cst[tid] = cn;
        float hn = sigm(ov) * tanhf(cn);
        gstore64(&hpub[(size_t)b * 8 + tid], tg | (unsigned long long)__float_as_uint(hn));
      }
    }

    // ---- C: poll tagged h; projections -> tagged slot words / out ----
    {
      s_co[tid] = pollw(&hpub[(size_t)(tid >> 2) * 8 + (tid & 3)], TT);
      lbar();
#pragma unroll
      for (int qi = 0; qi < 2; ++qi){
        int q = qi * 8 + wv;          // 0..15
        int pslot = q * 128 + b;
        if (pslot < 1292){
          const float* Wrow = nullptr; float bias = 0.f; int len = 512;
          int mode = 0;  // 0: tagged pub, 1: sigmoid + pub, 2: out store
          if (pslot < 256){ Wrow = w_Wk + (size_t)pslot * Hsz; bias = w_bk[pslot]; }
          else if (pslot < 512){ int i = pslot - 256; Wrow = w_We + (size_t)i * Hsz; bias = w_be[i]; mode = 1; }
          else if (pslot < 768){ int i = pslot - 512; Wrow = w_Wa + (size_t)i * Hsz; bias = w_ba[i]; }
          else if (pslot < 1024){ int i = pslot - 768; Wrow = r_Wk + (size_t)i * Hsz; bias = r_bk[i]; }
          else if (pslot < 1280){ int i = pslot - 1024; Wrow = Wo + (size_t)i * (Hsz + Dsz); bias = bo[i]; len = 768; mode = 2; }
          else {
            int i = pslot - 1280;
            int ii = (i >= 6) ? i - 6 : i;
            bool rh = (i >= 6);
            const float *Wt, *bt; int row = 0;
            if (ii == 0){ Wt = rh ? r_Wb : w_Wb; bt = rh ? r_bb : w_bb; }
            else if (ii == 1){ Wt = rh ? r_Wg : w_Wg; bt = rh ? r_bg : w_bg; }
            else if (ii == 2){ Wt = rh ? r_Wp : w_Wp; bt = rh ? r_bp : w_bp; }
            else { Wt = rh ? r_Ws : w_Ws; bt = rh ? r_bs : w_bs; row = ii - 3; }
            Wrow = Wt + (size_t)row * Hsz; bias = bt[row];
          }
          float acc = 0.f;
          if (len == 512){
            int k = ln * 8;
            float4 a0 = *(const float4*)(Wrow + k);
            float4 a1 = *(const float4*)(Wrow + k + 4);
            float4 c0 = *(const float4*)(&s_co[k]);
            float4 c1 = *(const float4*)(&s_co[k + 4]);
            acc = a0.x*c0.x + a0.y*c0.y + a0.z*c0.z + a0.w*c0.w
                + a1.x*c1.x + a1.y*c1.y + a1.z*c1.z + a1.w*c1.w;
          } else {
            int k = ln * 4;
            float4 w0 = *(const float4*)(Wrow + k);
            float4 w1 = *(const float4*)(Wrow + 256 + k);
            float4 w2 = *(const float4*)(Wrow + 512 + k);
            float4 c0 = *(const float4*)(&s_co[k]);
            float4 c1 = *(const float4*)(&s_co[256 + k]);
            float4 r0 = *(const float4*)(&s_rv[k]);
            acc = w0.x*c0.x + w0.y*c0.y + w0.z*c0.z + w0.w*c0.w
                + w1.x*c1.x + w1.y*c1.y + w1.z*c1.z + w1.w*c1.w
                + w2.x*r0.x + w2.y*r0.y + w2.z*r0.z + w2.w*r0.w;
          }
          acc = wred64(acc);
          if (ln == 0){
            float v = acc + bias;
            if (mode == 1) v = sigm(v);
            if (mode == 2) out[(size_t)t * Isz + (pslot - 1024)] = v;
            else gstore64(&ppub[pslot], tg | (unsigned long long)__float_as_uint(v));
          }
        }
      }
    }

    if (t == Tlen - 1) break;   // out(127) done; D..J only produce next-step state

    float betaR = 0.f, invbkR = 0.f;

    // ---- D: poll keyw+scal; write-head content scores (quad-per-row, DPP) ----
    {
      float* Pnx = Pbuf[(t + 1) & 1];
      if (b < NG && tid < 256) gstore(&Pnx[b * 256 + tid], 0.f);
      if (tid < 256) s_a[tid] = pollw(&ppub[tid], TT);
      else if (tid < 268) s_scal[tid - 256] = pollw(&ppub[1280 + (tid - 256)], TT);
      lbar();
      float nk2 = bred512((tid < 256) ? s_a[tid] * s_a[tid] : 0.f);
      float beta  = softplusf(s_scal[0]);
      float invbk = beta / fmaxf(sqrtf(nk2), 1e-12f);
      int row = tid >> 2, q = tid & 3;
      const float* mrow = &s_mem[row * Dsz];
      float d = 0.f;
#pragma unroll
      for (int k = 0; k < 16; ++k){
        int c = (q + 4 * ((k + row) & 15)) * 4;   // rotated chunk: bank spread
        float4 mv = *(const float4*)(mrow + c);
        float4 kv = *(const float4*)(&s_a[c]);
        d += mv.x*kv.x + mv.y*kv.y + mv.z*kv.z + mv.w*kv.w;
      }
      d = qsum4(d);
      if (q == 0) s_dot[row] = d;
      lbar();
      float e = 0.f;
      if (tid < RPB){
        float score = s_dot[tid] * invbk / fmaxf(s_norm[tid], 1e-12f);
        e = __expf(score - beta);
        s_e[tid] = e;
      }
      float tot = wred64(e);
      if (ln == 0 && wv < 2) s_w2[wv] = tot;
      lbar();
      if (tid == 0){
        float T = s_w2[0] + s_w2[1];
        gstore64(&wEF[b], tg | (unsigned long long)__float_as_uint(s_e[0]));
        gstore64(&wPF[b], tg | (unsigned long long)__float_as_uint(s_ww[0]));
        gstore64(&wEL[b], tg | (unsigned long long)__float_as_uint(s_e[RPB-1]));
        gstore64(&wPL[b], tg | (unsigned long long)__float_as_uint(s_ww[RPB-1]));
        atomicAdd(redD + slot * Tlen + t, fxpack(T));
      }
    }

    // ---- H-pre: poll er/ad/kr; Sw-independent reductions (quad-per-row) ----
    // mem_new = mv + ww*q, q = ad - mv*er  =>
    //   |mem_new|^2   = A0 + ww*A1 + ww^2*A2
    //   <mem_new,kr>  = B0 + ww*B1
    {
      if (tid < 256) s_er[tid] = pollw(&ppub[256 + tid], TT);          // erase (sigmoided)
      else           s_ad[tid - 256] = pollw(&ppub[512 + (tid - 256)], TT);  // add
      if (tid < 256) s_kr[tid] = pollw(&ppub[768 + tid], TT);          // keyr
      float nk2r = bred512((tid < 256) ? s_kr[tid] * s_kr[tid] : 0.f); // barriers inside
      betaR  = softplusf(s_scal[6]);
      invbkR = betaR / fmaxf(sqrtf(nk2r), 1e-12f);
      int row = tid >> 2, q = tid & 3;
      const float* mrow = &s_mem[row * Dsz];
      float mq = 0.f, qq = 0.f, qk = 0.f, mk = 0.f;
#pragma unroll
      for (int k = 0; k < 16; ++k){
        int c = (q + 4 * ((k + row) & 15)) * 4;
        float4 mv = *(const float4*)(mrow + c);
        float4 er = *(const float4*)(&s_er[c]);
        float4 ad = *(const float4*)(&s_ad[c]);
        float4 kr = *(const float4*)(&s_kr[c]);
        float qx = ad.x - mv.x * er.x;
        float qy = ad.y - mv.y * er.y;
        float qz = ad.z - mv.z * er.z;
        float qw = ad.w - mv.w * er.w;
        mq += mv.x*qx + mv.y*qy + mv.z*qz + mv.w*qw;
        qq += qx*qx + qy*qy + qz*qz + qw*qw;
        qk += qx*kr.x + qy*kr.y + qz*kr.z + qw*kr.w;
        mk += mv.x*kr.x + mv.y*kr.y + mv.z*kr.z + mv.w*kr.w;
      }
      mq = qsum4(mq); qq = qsum4(qq); qk = qsum4(qk); mk = qsum4(mk);
      if (q == 0){ s_A1[row] = 2.f*mq; s_A2[row] = qq; s_B1[row] = qk; s_B0[row] = mk; }
    }

    // ---- F: write-head shift+sharpen (S_w should already be there) ----
    {
      if (wv == 0 && ln < 4){
        const unsigned long long* bp = (ln == 0) ? &wEF[(b + 1) & (NBLK-1)]
                               : (ln == 1) ? &wPF[(b + 1) & (NBLK-1)]
                               : (ln == 2) ? &wEL[(b - 1) & (NBLK-1)]
                                           : &wPL[(b - 1) & (NBLK-1)];
        s_bd[ln] = pollw(bp, TT);
      }
      float S_w = redWait8(redD, t);
      shiftSharpen(0, s_ww, S_w, redF + slot * Tlen + t);
    }

    // ---- H-post: wait Sw; S_r fixups + publish FIRST, then mem update ----
    {
      float Sw = redWait8(redF, t);
      float invSw = 1.f / (Sw + 1e-8f);
      float4 er4 = *(const float4*)(&s_er[ln * 4]);
      float4 ad4 = *(const float4*)(&s_ad[ln * 4]);
      float e = 0.f;
      if (tid < RPB){
        float wwm = s_bw[tid] * invSw;
        s_ww[tid] = wwm;
        float A0 = s_norm[tid] * s_norm[tid];
        float n2 = fmaf(wwm, fmaf(wwm, s_A2[tid], s_A1[tid]), A0);
        float dt = fmaf(wwm, s_B1[tid], s_B0[tid]);
        float nr = sqrtf(fmaxf(n2, 0.f));
        s_norm[tid] = nr;
        float score = dt * invbkR / fmaxf(nr, 1e-12f);
        e = __expf(score - betaR);
        s_e[tid] = e;
      }
      float tot = wred64(e);
      if (ln == 0 && wv < 2) s_w2[wv] = tot;
      lbar();
      if (tid == 0){
        float T2 = s_w2[0] + s_w2[1];
        gstore64(&rEF[b], tg | (unsigned long long)__float_as_uint(s_e[0]));
        gstore64(&rPF[b], tg | (unsigned long long)__float_as_uint(s_rw[0]));
        gstore64(&rEL[b], tg | (unsigned long long)__float_as_uint(s_e[RPB-1]));
        gstore64(&rPL[b], tg | (unsigned long long)__float_as_uint(s_rw[RPB-1]));
        atomicAdd(redH + slot * Tlen + t, fxpack(T2));
      }
      // mem update runs while S_r propagates
#pragma unroll 1
      for (int it = 0; it < 16; ++it){
        int ml = it * 8 + wv;
        int off = ml * Dsz + ln * 4;
        float wwm = s_bw[ml] * invSw;
        float4 mv = *(const float4*)(&s_mem[off]);
        float4 nv;
        nv.x = fmaf(wwm, ad4.x - mv.x * er4.x, mv.x);
        nv.y = fmaf(wwm, ad4.y - mv.y * er4.y, mv.y);
        nv.z = fmaf(wwm, ad4.z - mv.z * er4.z, mv.z);
        nv.w = fmaf(wwm, ad4.w - mv.w * er4.w, mv.w);
        *(float4*)(&s_mem[off]) = nv;
      }
    }

    // ---- J: read sharpen; rvec partials; next-step GEMV hides redJ wait ----
    {
      if (wv == 0 && ln < 4){
        const unsigned long long* bp = (ln == 0) ? &rEF[(b + 1) & (NBLK-1)]
                               : (ln == 1) ? &rPF[(b + 1) & (NBLK-1)]
                               : (ln == 2) ? &rEL[(b - 1) & (NBLK-1)]
                                           : &rPL[(b - 1) & (NBLK-1)];
        s_bd[ln] = pollw(bp, TT);
      }
      float S_r = redWait8(redH, t);
      shiftSharpen(6, s_rw, S_r, nullptr);   // partial left in s_pub
      lbar();
      int col = tid & 255, half = tid >> 8;
      float acc = 0.f;
#pragma unroll 1
      for (int j = half * 64; j < half * 64 + 64; ++j) acc += s_bw[j] * s_mem[j * Dsz + col];
      if (half == 0) s_a[col] = acc;
      lbar();
      if (half == 1) atomicAdd(&Pcur[(b & (NG-1)) * 256 + col], acc + s_a[col]);
      __syncthreads();                       // drain atomics before publish
      if (tid == 0) atomicAdd(redJ + slot * Tlen + t, fxpack(s_pub));
      // hide the redJ wait under next step's x/h GEMV parts
      if (tid < 256) s_a[tid] = inputs[(size_t)(t + 1) * Isz + tid];
      lbar();
      accxh = gemvXH();
      Srcarry = redWait8(redJ, t);
    }
  }
}

extern "C" void kernel_launch(void* const* d_in, const int* in_sizes, int n_in,
                              void* d_out, int out_size, void* d_ws, size_t ws_size,
                              hipStream_t stream)
{
  (void)in_sizes; (void)out_size;
  if (n_in < 34) return;
  if (ws_size < (size_t)98304) return;
  Params P;
  for (int i = 0; i < 34; ++i) P.in[i] = (const float*)d_in[i];
  P.out = (float*)d_out;
  P.ws  = (float*)d_ws;
  hipLaunchKernelGGL(ntm_kernel, dim3(NBLK), dim3(NTHR), 0, stream, P);
}